// Round 1
// baseline (414.627 us; speedup 1.0000x reference)
//
#include <hip/hip_runtime.h>
#include <stdint.h>

// ---------------------------------------------------------------------------
// Fused SAM-style attention block on MI355X (gfx950).
// Pipeline: W_eff=w_qkv+loraB@loraA -> QKV GEMM (bf16 MFMA) -> vT transpose
//           -> rel_h/rel_w precompute -> flash attention (bf16 MFMA, online
//           softmax, decomposed rel-pos bias) -> fp32 output projection.
// ---------------------------------------------------------------------------

typedef __attribute__((ext_vector_type(4))) float f32x4;
typedef __attribute__((ext_vector_type(4))) float fvec4;
typedef __attribute__((ext_vector_type(8))) short s16x8;
typedef __attribute__((ext_vector_type(4))) short s16x4;

constexpr int NH  = 12;
constexpr int HD  = 64;
constexpr int DIM = 768;
constexpr int N   = 4096;   // 64 x 64 spatial
constexpr int QKV = 2304;
constexpr float SCALE = 0.125f;  // 64^-0.5

static __device__ __forceinline__ short f2bf(float f) {
  unsigned u = __builtin_bit_cast(unsigned, f);
  unsigned r = (u + 0x7FFFu + ((u >> 16) & 1u)) >> 16;  // RNE
  return (short)r;
}
static __device__ __forceinline__ float bf2f(short s) {
  unsigned u = ((unsigned)(unsigned short)s) << 16;
  return __builtin_bit_cast(float, u);
}

// ---------------------------------------------------------------------------
// K0: W_eff[r][c] = w_qkv[r][c] + sum_t lora_B[r][t] * lora_A[t][c]  (bf16 out)
// ---------------------------------------------------------------------------
__global__ __launch_bounds__(256) void k_weff(const float* __restrict__ w_qkv,
                                              const float* __restrict__ lora_A,
                                              const float* __restrict__ lora_B,
                                              short* __restrict__ weff) {
  int e = blockIdx.x * 256 + threadIdx.x;
  if (e >= QKV * DIM) return;
  int r = e / DIM, c = e % DIM;
  float acc = w_qkv[e];
#pragma unroll
  for (int t = 0; t < 12; ++t) acc += lora_B[r * 12 + t] * lora_A[t * DIM + c];
  weff[e] = f2bf(acc);
}

// ---------------------------------------------------------------------------
// K1: qkv = x @ W_eff^T + b_qkv ; scatter into q/k/v [head][i][hd] bf16.
// 64x64 tile, BK=64, 4 waves, mfma_f32_16x16x32_bf16.
// ---------------------------------------------------------------------------
__global__ __launch_bounds__(256) void k_qkv(const float* __restrict__ x,
                                             const short* __restrict__ weff,
                                             const float* __restrict__ b_qkv,
                                             short* __restrict__ qg,
                                             short* __restrict__ kg,
                                             short* __restrict__ vg) {
  __shared__ short xs[64 * 72];   // pad 8 shorts: stride 144B -> 2-way only
  __shared__ short ws2[64 * 72];
  const int tid = threadIdx.x;
  const int i0 = blockIdx.x * 64;
  const int j0 = blockIdx.y * 64;
  const int wave = tid >> 6, lane = tid & 63, lr = lane & 15, lg = lane >> 4;

  f32x4 acc[4] = {};

  for (int kt = 0; kt < 12; ++kt) {
    const int c0 = kt * 64;
    // stage x tile (fp32 -> bf16)
#pragma unroll
    for (int it = 0; it < 4; ++it) {
      int idx = tid + 256 * it;
      int row = idx >> 4, c4 = (idx & 15) * 4;
      fvec4 v = *reinterpret_cast<const fvec4*>(&x[(size_t)(i0 + row) * DIM + c0 + c4]);
      s16x4 p;
      p[0] = f2bf(v[0]); p[1] = f2bf(v[1]); p[2] = f2bf(v[2]); p[3] = f2bf(v[3]);
      *reinterpret_cast<s16x4*>(&xs[row * 72 + c4]) = p;
    }
    // stage W_eff tile (already bf16)
#pragma unroll
    for (int it = 0; it < 2; ++it) {
      int idx = tid + 256 * it;
      int row = idx >> 3, ch = (idx & 7) * 8;
      *reinterpret_cast<s16x8*>(&ws2[row * 72 + ch]) =
          *reinterpret_cast<const s16x8*>(&weff[(size_t)(j0 + row) * DIM + c0 + ch]);
    }
    __syncthreads();
#pragma unroll
    for (int ks = 0; ks < 2; ++ks) {
      s16x8 a = *reinterpret_cast<const s16x8*>(&xs[(wave * 16 + lr) * 72 + ks * 32 + lg * 8]);
#pragma unroll
      for (int n = 0; n < 4; ++n) {
        s16x8 b = *reinterpret_cast<const s16x8*>(&ws2[(n * 16 + lr) * 72 + ks * 32 + lg * 8]);
        acc[n] = __builtin_amdgcn_mfma_f32_16x16x32_bf16(a, b, acc[n], 0, 0, 0);
      }
    }
    __syncthreads();
  }

  // epilogue: whole block lives inside one (three, head) 64-column segment
  const int three = j0 / DIM;
  const int head = (j0 % DIM) / HD;
  short* dst = (three == 0) ? qg : ((three == 1) ? kg : vg);
#pragma unroll
  for (int n = 0; n < 4; ++n) {
#pragma unroll
    for (int r = 0; r < 4; ++r) {
      int row = i0 + wave * 16 + lg * 4 + r;
      int j = j0 + n * 16 + lr;
      float val = acc[n][r] + b_qkv[j];
      dst[((size_t)head * N + row) * HD + (n * 16 + lr)] = f2bf(val);
    }
  }
}

// ---------------------------------------------------------------------------
// K1b: vT[h][c][i] = v[h][i][c]  (LDS tile transpose)
// ---------------------------------------------------------------------------
__global__ __launch_bounds__(256) void k_vT(const short* __restrict__ vg,
                                            short* __restrict__ vTg) {
  __shared__ short ts[64 * 72];
  const int tid = threadIdx.x;
  const int i0 = blockIdx.x * 64;
  const int h = blockIdx.y;
#pragma unroll
  for (int it = 0; it < 2; ++it) {
    int ch = tid + 256 * it;
    int row = ch >> 3, cc = (ch & 7) * 8;
    *reinterpret_cast<s16x8*>(&ts[row * 72 + cc]) =
        *reinterpret_cast<const s16x8*>(&vg[((size_t)h * N + i0 + row) * HD + cc]);
  }
  __syncthreads();
#pragma unroll
  for (int it = 0; it < 2; ++it) {
    int ch = tid + 256 * it;
    int c = ch >> 3, ii = (ch & 7) * 8;
    s16x8 o;
#pragma unroll
    for (int j = 0; j < 8; ++j) o[j] = ts[(ii + j) * 72 + c];
    *reinterpret_cast<s16x8*>(&vTg[((size_t)h * HD + c) * N + i0 + ii]) = o;
  }
}

// ---------------------------------------------------------------------------
// K2: decomposed rel-pos bias precompute.
// MODE 0: rel_h[h][qh][qw][kh] = dot(q[h][qh*64+qw][:], rel_pos_h[qh-kh+63][:])
// MODE 1: rel_w[h][qh][qw][kw] = dot(q[h][qh*64+qw][:], rel_pos_w[qw-kw+63][:])
// One block per (h, qh). Output bf16.
// ---------------------------------------------------------------------------
template <int MODE>
__global__ __launch_bounds__(256) void k_rel(const short* __restrict__ qg,
                                             const float* __restrict__ tab,
                                             short* __restrict__ outg) {
  __shared__ float qs[64 * 65];
  __shared__ float ts[127 * 65];
  const int tid = threadIdx.x;
  const int h = blockIdx.x >> 6, qh = blockIdx.x & 63;
  for (int e = tid; e < 64 * 64; e += 256) {
    int qw = e >> 6, c = e & 63;
    qs[qw * 65 + c] = bf2f(qg[((size_t)h * N + qh * 64 + qw) * HD + c]);
  }
  for (int e = tid; e < 127 * 64; e += 256) {
    int rr = e >> 6, c = e & 63;
    ts[rr * 65 + c] = tab[e];
  }
  __syncthreads();
  const size_t obase = ((size_t)(h * 64 + qh)) * 64 * 64;
  for (int e = tid; e < 4096; e += 256) {
    int qw = e >> 6, kc = e & 63;
    int trow = (MODE == 0 ? qh : qw) - kc + 63;
    const float* qrow = &qs[qw * 65];
    const float* tr = &ts[trow * 65];
    float acc = 0.f;
#pragma unroll 8
    for (int c = 0; c < 64; ++c) acc += qrow[c] * tr[c];
    outg[obase + e] = f2bf(acc);
  }
}

// ---------------------------------------------------------------------------
// K3: flash attention. One block = (head h, q-tile of 64 rows == one qh row).
// k-tile t = one kh row (64 keys). 4 waves, each owns 16 q-rows x 64 cols.
// S = q.k^T*SCALE + rel_h[qrow][t] + rel_w[qrow][kw]; online softmax; O += P.V
// ---------------------------------------------------------------------------
__global__ __launch_bounds__(256) void k_flash(const short* __restrict__ qg,
                                               const short* __restrict__ kg,
                                               const short* __restrict__ vTg,
                                               const short* __restrict__ relh,
                                               const short* __restrict__ relw,
                                               float* __restrict__ Og) {
  __shared__ short qs[64 * 72];
  __shared__ short ks_[64 * 72];
  __shared__ short vts[64 * 72];   // vts[c][kk] = v[k0+kk][c]
  __shared__ short ps[64 * 72];
  __shared__ short rhT[64 * 72];   // rhT[kh][qw]
  const int tid = threadIdx.x;
  const int h = blockIdx.x >> 6, qt = blockIdx.x & 63;
  const int i0 = qt * 64;
  const int wave = tid >> 6, lane = tid & 63, lr = lane & 15, lg = lane >> 4;

  // stage q tile
#pragma unroll
  for (int it = 0; it < 2; ++it) {
    int ch = tid + 256 * it;
    int row = ch >> 3, cc = (ch & 7) * 8;
    *reinterpret_cast<s16x8*>(&qs[row * 72 + cc]) =
        *reinterpret_cast<const s16x8*>(&qg[((size_t)h * N + i0 + row) * HD + cc]);
  }
  // stage rel_h slab transposed: [qw][kh] -> [kh][qw]
  const size_t rbase = ((size_t)(h * 64 + qt)) * 4096;
#pragma unroll
  for (int it = 0; it < 16; ++it) {
    int e = tid + 256 * it;
    int qw = e >> 6, kh = e & 63;
    rhT[kh * 72 + qw] = relh[rbase + e];
  }
  // preload rel_w for this lane's 16 (row, kw) cells into registers
  float rw[4][4];
#pragma unroll
  for (int n = 0; n < 4; ++n)
#pragma unroll
    for (int r = 0; r < 4; ++r) {
      int row = wave * 16 + lg * 4 + r;
      rw[n][r] = bf2f(relw[rbase + (size_t)row * 64 + n * 16 + lr]);
    }

  f32x4 acc_o[4] = {};
  float m[4], l[4];
#pragma unroll
  for (int r = 0; r < 4; ++r) { m[r] = -1e30f; l[r] = 0.f; }

  for (int t = 0; t < 64; ++t) {
    // stage k-tile and vT-tile
#pragma unroll
    for (int it = 0; it < 2; ++it) {
      int ch = tid + 256 * it;
      int row = ch >> 3, cc = (ch & 7) * 8;
      *reinterpret_cast<s16x8*>(&ks_[row * 72 + cc]) =
          *reinterpret_cast<const s16x8*>(&kg[((size_t)h * N + t * 64 + row) * HD + cc]);
      *reinterpret_cast<s16x8*>(&vts[row * 72 + cc]) =
          *reinterpret_cast<const s16x8*>(&vTg[((size_t)h * HD + row) * N + t * 64 + cc]);
    }
    __syncthreads();

    // S = q.k^T
    f32x4 sa[4] = {};
#pragma unroll
    for (int ks2 = 0; ks2 < 2; ++ks2) {
      s16x8 a = *reinterpret_cast<const s16x8*>(&qs[(wave * 16 + lr) * 72 + ks2 * 32 + lg * 8]);
#pragma unroll
      for (int n = 0; n < 4; ++n) {
        s16x8 b = *reinterpret_cast<const s16x8*>(&ks_[(n * 16 + lr) * 72 + ks2 * 32 + lg * 8]);
        sa[n] = __builtin_amdgcn_mfma_f32_16x16x32_bf16(a, b, sa[n], 0, 0, 0);
      }
    }

    // bias + scale; per-row online softmax (rows live in 16-lane groups)
    s16x4 rh4 = *reinterpret_cast<const s16x4*>(&rhT[t * 72 + wave * 16 + lg * 4]);
    float sv[4][4], mt[4];
#pragma unroll
    for (int r = 0; r < 4; ++r) mt[r] = -1e30f;
#pragma unroll
    for (int n = 0; n < 4; ++n)
#pragma unroll
      for (int r = 0; r < 4; ++r) {
        float s = sa[n][r] * SCALE + bf2f(rh4[r]) + rw[n][r];
        sv[n][r] = s;
        mt[r] = fmaxf(mt[r], s);
      }
#pragma unroll
    for (int mask = 1; mask < 16; mask <<= 1)
#pragma unroll
      for (int r = 0; r < 4; ++r) mt[r] = fmaxf(mt[r], __shfl_xor(mt[r], mask));

    float corr[4], psum[4];
#pragma unroll
    for (int r = 0; r < 4; ++r) {
      float mn = fmaxf(m[r], mt[r]);
      corr[r] = __expf(m[r] - mn);
      m[r] = mn;
      psum[r] = 0.f;
    }
#pragma unroll
    for (int n = 0; n < 4; ++n)
#pragma unroll
      for (int r = 0; r < 4; ++r) {
        float p = __expf(sv[n][r] - m[r]);
        psum[r] += p;
        ps[(wave * 16 + lg * 4 + r) * 72 + n * 16 + lr] = f2bf(p);
      }
#pragma unroll
    for (int mask = 1; mask < 16; mask <<= 1)
#pragma unroll
      for (int r = 0; r < 4; ++r) psum[r] += __shfl_xor(psum[r], mask);
#pragma unroll
    for (int r = 0; r < 4; ++r) l[r] = l[r] * corr[r] + psum[r];
#pragma unroll
    for (int n = 0; n < 4; ++n)
#pragma unroll
      for (int r = 0; r < 4; ++r) acc_o[n][r] *= corr[r];

    // O += P.V  (A from own ps rows; B from vts)
#pragma unroll
    for (int ks2 = 0; ks2 < 2; ++ks2) {
      s16x8 a = *reinterpret_cast<const s16x8*>(&ps[(wave * 16 + lr) * 72 + ks2 * 32 + lg * 8]);
#pragma unroll
      for (int n = 0; n < 4; ++n) {
        s16x8 b = *reinterpret_cast<const s16x8*>(&vts[(n * 16 + lr) * 72 + ks2 * 32 + lg * 8]);
        acc_o[n] = __builtin_amdgcn_mfma_f32_16x16x32_bf16(a, b, acc_o[n], 0, 0, 0);
      }
    }
    __syncthreads();
  }

  // epilogue: O /= l, fp32 store
#pragma unroll
  for (int r = 0; r < 4; ++r) {
    float inv = 1.f / l[r];
    int row = i0 + wave * 16 + lg * 4 + r;
#pragma unroll
    for (int n = 0; n < 4; ++n)
      Og[((size_t)h * N + row) * HD + n * 16 + lr] = acc_o[n][r] * inv;
  }
}

// ---------------------------------------------------------------------------
// K4: out[i][e] = sum_f O[f/64][i][f%64] * w_proj[e][f] + b_proj[e]  (fp32)
// Accuracy-critical direct path: stays fp32 VALU. 64x64 tile, BK=64.
// ---------------------------------------------------------------------------
__global__ __launch_bounds__(256) void k_proj(const float* __restrict__ Og,
                                              const float* __restrict__ w_proj,
                                              const float* __restrict__ b_proj,
                                              float* __restrict__ out) {
  __shared__ float As[64 * 65];
  __shared__ float Bs[64 * 65];
  const int tid = threadIdx.x;
  const int tx = tid & 15, ty = tid >> 4;
  const int i0 = blockIdx.x * 64, e0 = blockIdx.y * 64;
  float acc[4][4] = {};
  for (int kt = 0; kt < 12; ++kt) {
    const int f0 = kt * 64;  // head = kt, c = ff
#pragma unroll
    for (int it = 0; it < 4; ++it) {
      int idx = tid + 256 * it;
      int row = idx >> 4, c4 = (idx & 15) * 4;
      fvec4 va = *reinterpret_cast<const fvec4*>(&Og[((size_t)kt * N + i0 + row) * HD + c4]);
      As[row * 65 + c4 + 0] = va[0]; As[row * 65 + c4 + 1] = va[1];
      As[row * 65 + c4 + 2] = va[2]; As[row * 65 + c4 + 3] = va[3];
      fvec4 vb = *reinterpret_cast<const fvec4*>(&w_proj[(size_t)(e0 + row) * DIM + f0 + c4]);
      Bs[row * 65 + c4 + 0] = vb[0]; Bs[row * 65 + c4 + 1] = vb[1];
      Bs[row * 65 + c4 + 2] = vb[2]; Bs[row * 65 + c4 + 3] = vb[3];
    }
    __syncthreads();
#pragma unroll 8
    for (int f = 0; f < 64; ++f) {
      float a[4], b[4];
#pragma unroll
      for (int u = 0; u < 4; ++u) a[u] = As[(ty * 4 + u) * 65 + f];
#pragma unroll
      for (int u = 0; u < 4; ++u) b[u] = Bs[(tx * 4 + u) * 65 + f];
#pragma unroll
      for (int u = 0; u < 4; ++u)
#pragma unroll
        for (int v = 0; v < 4; ++v) acc[u][v] += a[u] * b[v];
    }
    __syncthreads();
  }
#pragma unroll
  for (int u = 0; u < 4; ++u)
#pragma unroll
    for (int v = 0; v < 4; ++v)
      out[(size_t)(i0 + ty * 4 + u) * DIM + e0 + tx * 4 + v] =
          acc[u][v] + b_proj[e0 + tx * 4 + v];
}

// ---------------------------------------------------------------------------
extern "C" void kernel_launch(void* const* d_in, const int* in_sizes, int n_in,
                              void* d_out, int out_size, void* d_ws, size_t ws_size,
                              hipStream_t stream) {
  const float* x      = (const float*)d_in[0];
  const float* w_qkv  = (const float*)d_in[1];
  const float* b_qkv  = (const float*)d_in[2];
  const float* lora_A = (const float*)d_in[3];
  const float* lora_B = (const float*)d_in[4];
  const float* w_proj = (const float*)d_in[5];
  const float* b_proj = (const float*)d_in[6];
  const float* rel_h  = (const float*)d_in[7];
  const float* rel_w  = (const float*)d_in[8];
  float* out = (float*)d_out;

  char* ws = (char*)d_ws;
  size_t off = 0;
  auto alloc = [&](size_t bytes) {
    char* p = ws + off;
    off += (bytes + 255) & ~(size_t)255;
    return p;
  };
  short* weff = (short*)alloc((size_t)QKV * DIM * 2);        // 3.5 MB
  short* qg   = (short*)alloc((size_t)NH * N * HD * 2);      // 6.3 MB
  short* kg   = (short*)alloc((size_t)NH * N * HD * 2);
  short* vg   = (short*)alloc((size_t)NH * N * HD * 2);
  short* vTg  = (short*)alloc((size_t)NH * N * HD * 2);
  short* rhg  = (short*)alloc((size_t)NH * 64 * 64 * 64 * 2);
  short* rwg  = (short*)alloc((size_t)NH * 64 * 64 * 64 * 2);
  float* Og   = (float*)alloc((size_t)NH * N * HD * 4);      // 12.6 MB
  (void)ws_size; (void)in_sizes; (void)n_in; (void)out_size; // ~54 MB total

  k_weff<<<dim3((QKV * DIM + 255) / 256), dim3(256), 0, stream>>>(w_qkv, lora_A, lora_B, weff);
  k_qkv<<<dim3(64, 36), dim3(256), 0, stream>>>(x, weff, b_qkv, qg, kg, vg);
  k_vT<<<dim3(64, NH), dim3(256), 0, stream>>>(vg, vTg);
  k_rel<0><<<dim3(NH * 64), dim3(256), 0, stream>>>(qg, rel_h, rhg);
  k_rel<1><<<dim3(NH * 64), dim3(256), 0, stream>>>(qg, rel_w, rwg);
  k_flash<<<dim3(NH * 64), dim3(256), 0, stream>>>(qg, kg, vTg, rhg, rwg, Og);
  k_proj<<<dim3(64, 12), dim3(256), 0, stream>>>(Og, w_proj, b_proj, out);
}

// Round 2
// 208.991 us; speedup vs baseline: 1.9840x; 1.9840x over previous
//
#include <hip/hip_runtime.h>
#include <stdint.h>

// ---------------------------------------------------------------------------
// Fused SAM-style attention block on MI355X (gfx950).  Round 2.
// x->bf16 -> W_eff -> QKV GEMM (128x128 MFMA, global_load_lds + XOR swizzle)
// -> vT -> rel_h / rel_w (MFMA) -> flash attn (static softmax, dbuf K/V,
// split-bf16 O output) -> proj GEMM (split-bf16 MFMA, fp32 out).
// ---------------------------------------------------------------------------

typedef __attribute__((ext_vector_type(4))) float f32x4;
typedef __attribute__((ext_vector_type(4))) float fvec4;
typedef __attribute__((ext_vector_type(8))) short s16x8;
typedef __attribute__((ext_vector_type(4))) short s16x4;

constexpr int NH  = 12;
constexpr int HD  = 64;
constexpr int DIM = 768;
constexpr int N   = 4096;
constexpr int QKV = 2304;
constexpr float SCALE = 0.125f;

static __device__ __forceinline__ short f2bf(float f) {
  unsigned u = __builtin_bit_cast(unsigned, f);
  unsigned r = (u + 0x7FFFu + ((u >> 16) & 1u)) >> 16;  // RNE
  return (short)r;
}
static __device__ __forceinline__ float bf2f(short s) {
  unsigned u = ((unsigned)(unsigned short)s) << 16;
  return __builtin_bit_cast(float, u);
}
static __device__ __forceinline__ unsigned cvt_pk_bf16(float a, float b) {
  unsigned r;
  asm("v_cvt_pk_bf16_f32 %0, %1, %2" : "=v"(r) : "v"(a), "v"(b));
  return r;
}
// async global->LDS, 16B per lane. LDS dest must be wave-uniform base.
static __device__ __forceinline__ void gload16(const void* g, void* l) {
  __builtin_amdgcn_global_load_lds(
      (const __attribute__((address_space(1))) void*)g,
      (__attribute__((address_space(3))) void*)l, 16, 0, 0);
}

// ---------------------------------------------------------------------------
// K0: W_eff = w_qkv + lora_B @ lora_A  (bf16 out, [2304][768])
// ---------------------------------------------------------------------------
__global__ __launch_bounds__(256) void k_weff(const float* __restrict__ w_qkv,
                                              const float* __restrict__ lora_A,
                                              const float* __restrict__ lora_B,
                                              short* __restrict__ weff) {
  int e = blockIdx.x * 256 + threadIdx.x;
  if (e >= QKV * DIM) return;
  int r = e / DIM, c = e % DIM;
  float acc = w_qkv[e];
#pragma unroll
  for (int t = 0; t < 12; ++t) acc += lora_B[r * 12 + t] * lora_A[t * DIM + c];
  weff[e] = f2bf(acc);
}

// ---------------------------------------------------------------------------
// K0b: x fp32 -> bf16  ([4096][768])
// ---------------------------------------------------------------------------
__global__ __launch_bounds__(256) void k_x2bf(const float* __restrict__ x,
                                              short* __restrict__ xb) {
  int i = blockIdx.x * 256 + threadIdx.x;  // one float4 per thread, grid 3072
  fvec4 v = *reinterpret_cast<const fvec4*>(x + (size_t)i * 4);
  s16x4 p;
  p[0] = f2bf(v[0]); p[1] = f2bf(v[1]); p[2] = f2bf(v[2]); p[3] = f2bf(v[3]);
  *reinterpret_cast<s16x4*>(xb + (size_t)i * 4) = p;
}

// ---------------------------------------------------------------------------
// K0c: w_proj -> split-bf16 B' [768][2304] = [Whi | Wlo | Whi]
// ---------------------------------------------------------------------------
__global__ __launch_bounds__(256) void k_wsplit(const float* __restrict__ w,
                                                short* __restrict__ ws) {
  int r = blockIdx.y;
  int kk = blockIdx.x * 256 + threadIdx.x;  // grid (9, 768)
  int blk = (kk >= 1536) ? 2 : (kk >= 768 ? 1 : 0);
  int c = kk - blk * 768;
  float wv = w[(size_t)r * 768 + c];
  short hi = f2bf(wv);
  ws[(size_t)r * 2304 + kk] = (blk == 1) ? f2bf(wv - bf2f(hi)) : hi;
}

// ---------------------------------------------------------------------------
// Shared 128x128 MFMA GEMM, BK=64, single-buffer 2-barrier (m97 structure).
// A [M][K] bf16, B [Ncols][K] bf16 (B^T-GEMM).  MODE 0: qkv scatter epilogue.
// MODE 1: fp32 out + bias.
// ---------------------------------------------------------------------------
template <int KIT, int MODE>
__global__ __launch_bounds__(256) void k_gemm(const short* __restrict__ A,
                                              const short* __restrict__ B,
                                              const float* __restrict__ bias,
                                              short* __restrict__ qo,
                                              short* __restrict__ ko,
                                              short* __restrict__ vo,
                                              float* __restrict__ outf) {
  __shared__ __align__(16) char lds[32768];  // A @0, B @16384
  const int tid = threadIdx.x;
  const int wave = tid >> 6, lane = tid & 63, lr = lane & 15, lg = lane >> 4;
  const int wr = wave >> 1, wc = wave & 1;
  const int i0 = blockIdx.x * 128, j0 = blockIdx.y * 128;
  const int LDA = KIT * 128;  // row bytes

  // staging: 1024 chunks of 16B per tile, 4 per thread
  size_t aoff[4];
#pragma unroll
  for (int it = 0; it < 4; ++it) {
    int c = it * 256 + wave * 64 + lane;
    int row = c >> 3;
    aoff[it] = (size_t)row * LDA + (((c & 7) << 4) ^ ((row & 7) << 4));
  }
  const char* Ab = (const char*)A + (size_t)i0 * LDA;
  const char* Bb = (const char*)B + (size_t)j0 * LDA;
  char* la = lds + wave * 1024;
  char* lb = lds + 16384 + wave * 1024;

  const int swz = (lr & 7) << 4;
  const int ab = (wr * 64 + lr) * 128 + ((lg * 16) ^ swz);
  const int bb = 16384 + (wc * 64 + lr) * 128 + ((lg * 16) ^ swz);

  f32x4 acc[4][4] = {};

  for (int kt = 0; kt < KIT; ++kt) {
    const size_t kadd = (size_t)kt * 128;
#pragma unroll
    for (int it = 0; it < 4; ++it) gload16(Ab + kadd + aoff[it], la + it * 4096);
#pragma unroll
    for (int it = 0; it < 4; ++it) gload16(Bb + kadd + aoff[it], lb + it * 4096);
    __syncthreads();
#pragma unroll
    for (int ks2 = 0; ks2 < 2; ++ks2) {
      s16x8 af[4], bf_[4];
#pragma unroll
      for (int m = 0; m < 4; ++m)
        af[m] = *reinterpret_cast<const s16x8*>(lds + ((ab + m * 2048) ^ (ks2 << 6)));
#pragma unroll
      for (int n = 0; n < 4; ++n)
        bf_[n] = *reinterpret_cast<const s16x8*>(lds + ((bb + n * 2048) ^ (ks2 << 6)));
#pragma unroll
      for (int m = 0; m < 4; ++m)
#pragma unroll
        for (int n = 0; n < 4; ++n)
          acc[m][n] = __builtin_amdgcn_mfma_f32_16x16x32_bf16(af[m], bf_[n], acc[m][n], 0, 0, 0);
    }
    __syncthreads();
  }

  if constexpr (MODE == 0) {
    const int three = j0 / 768;
    const int head = ((j0 % 768) >> 6) + wc;
    short* dst = (three == 0) ? qo : ((three == 1) ? ko : vo);
#pragma unroll
    for (int n = 0; n < 4; ++n) {
      const int col = n * 16 + lr;
      const float bj = bias[j0 + wc * 64 + col];
#pragma unroll
      for (int m = 0; m < 4; ++m)
#pragma unroll
        for (int r = 0; r < 4; ++r) {
          int i = i0 + wr * 64 + m * 16 + lg * 4 + r;
          dst[((size_t)head * N + i) * HD + col] = f2bf(acc[m][n][r] + bj);
        }
    }
  } else {
#pragma unroll
    for (int n = 0; n < 4; ++n) {
      const int j = j0 + wc * 64 + n * 16 + lr;
      const float bj = bias[j];
#pragma unroll
      for (int m = 0; m < 4; ++m)
#pragma unroll
        for (int r = 0; r < 4; ++r) {
          int i = i0 + wr * 64 + m * 16 + lg * 4 + r;
          outf[(size_t)i * 768 + j] = acc[m][n][r] + bj;
        }
    }
  }
}

// ---------------------------------------------------------------------------
// K1b: vT[h][c][i] = v[h][i][c]
// ---------------------------------------------------------------------------
__global__ __launch_bounds__(256) void k_vT(const short* __restrict__ vg,
                                            short* __restrict__ vTg) {
  __shared__ short ts[64 * 72];
  const int tid = threadIdx.x;
  const int i0 = blockIdx.x * 64;
  const int h = blockIdx.y;
#pragma unroll
  for (int it = 0; it < 2; ++it) {
    int ch = tid + 256 * it;
    int row = ch >> 3, cc = (ch & 7) * 8;
    *reinterpret_cast<s16x8*>(&ts[row * 72 + cc]) =
        *reinterpret_cast<const s16x8*>(&vg[((size_t)h * N + i0 + row) * HD + cc]);
  }
  __syncthreads();
#pragma unroll
  for (int it = 0; it < 2; ++it) {
    int ch = tid + 256 * it;
    int c = ch >> 3, ii = (ch & 7) * 8;
    s16x8 o;
#pragma unroll
    for (int j = 0; j < 8; ++j) o[j] = ts[(ii + j) * 72 + c];
    *reinterpret_cast<s16x8*>(&vTg[((size_t)h * HD + c) * N + i0 + ii]) = o;
  }
}

// ---------------------------------------------------------------------------
// K2a: rel_h via MFMA, stored TRANSPOSED: rhT[h][qh][kh][qw]
// out[qw][kh] = sum_c q[h][qh*64+qw][c] * tab[qh-kh+63][c]
// ---------------------------------------------------------------------------
__global__ __launch_bounds__(256) void k_relh(const short* __restrict__ qg,
                                              const float* __restrict__ tab,
                                              short* __restrict__ rhT) {
  __shared__ short Ts[64 * 72];
  const int tid = threadIdx.x;
  const int wave = tid >> 6, lane = tid & 63, lr = lane & 15, lg = lane >> 4;
  const int h = blockIdx.x >> 6, qh = blockIdx.x & 63;
#pragma unroll
  for (int it = 0; it < 4; ++it) {
    int e = tid + 256 * it;
    int row = e >> 4, c4 = (e & 15) * 4;  // row = kh
    fvec4 v = *reinterpret_cast<const fvec4*>(tab + (size_t)(qh + 63 - row) * 64 + c4);
    s16x4 p;
    p[0] = f2bf(v[0]); p[1] = f2bf(v[1]); p[2] = f2bf(v[2]); p[3] = f2bf(v[3]);
    *reinterpret_cast<s16x4*>(&Ts[row * 72 + c4]) = p;
  }
  __syncthreads();
  const size_t qrow = (size_t)h * N + qh * 64 + wave * 16 + lr;
  const s16x8 a0 = *reinterpret_cast<const s16x8*>(qg + qrow * 64 + lg * 8);
  const s16x8 a1 = *reinterpret_cast<const s16x8*>(qg + qrow * 64 + 32 + lg * 8);
  f32x4 acc[4] = {};
#pragma unroll
  for (int ks2 = 0; ks2 < 2; ++ks2)
#pragma unroll
    for (int n = 0; n < 4; ++n) {
      s16x8 b = *reinterpret_cast<const s16x8*>(&Ts[(n * 16 + lr) * 72 + ks2 * 32 + lg * 8]);
      acc[n] = __builtin_amdgcn_mfma_f32_16x16x32_bf16(ks2 ? a1 : a0, b, acc[n], 0, 0, 0);
    }
  const size_t ob = ((size_t)(h * 64 + qh)) * 4096;
#pragma unroll
  for (int n = 0; n < 4; ++n) {
    s16x4 o;
#pragma unroll
    for (int r = 0; r < 4; ++r) o[r] = f2bf(acc[n][r]);
    *reinterpret_cast<s16x4*>(&rhT[ob + (size_t)(n * 16 + lr) * 64 + wave * 16 + lg * 4]) = o;
  }
}

// ---------------------------------------------------------------------------
// K2b: rel_w via U-GEMM + scatter.  U[qw][d] = sum_c q[..][c]*tab[d][c],
// rwg[h][i][kw] = U[qw][qw-kw+63]   (i = qh*64+qw)
// ---------------------------------------------------------------------------
__global__ __launch_bounds__(256) void k_relw(const short* __restrict__ qg,
                                              const float* __restrict__ tab,
                                              short* __restrict__ rwg) {
  __shared__ short Ts[128 * 72];
  const int tid = threadIdx.x;
  const int wave = tid >> 6, lane = tid & 63, lr = lane & 15, lg = lane >> 4;
  const int h = blockIdx.x >> 6, qh = blockIdx.x & 63;
#pragma unroll
  for (int it = 0; it < 8; ++it) {
    int e = tid + 256 * it;
    int row = e >> 4, c4 = (e & 15) * 4;  // row = d
    s16x4 p = {0, 0, 0, 0};
    if (row < 127) {
      fvec4 v = *reinterpret_cast<const fvec4*>(tab + (size_t)row * 64 + c4);
      p[0] = f2bf(v[0]); p[1] = f2bf(v[1]); p[2] = f2bf(v[2]); p[3] = f2bf(v[3]);
    }
    *reinterpret_cast<s16x4*>(&Ts[row * 72 + c4]) = p;
  }
  __syncthreads();
  const size_t qrow = (size_t)h * N + qh * 64 + wave * 16 + lr;
  const s16x8 a0 = *reinterpret_cast<const s16x8*>(qg + qrow * 64 + lg * 8);
  const s16x8 a1 = *reinterpret_cast<const s16x8*>(qg + qrow * 64 + 32 + lg * 8);
  f32x4 acc[8] = {};
#pragma unroll
  for (int ks2 = 0; ks2 < 2; ++ks2)
#pragma unroll
    for (int n = 0; n < 8; ++n) {
      s16x8 b = *reinterpret_cast<const s16x8*>(&Ts[(n * 16 + lr) * 72 + ks2 * 32 + lg * 8]);
      acc[n] = __builtin_amdgcn_mfma_f32_16x16x32_bf16(ks2 ? a1 : a0, b, acc[n], 0, 0, 0);
    }
  const size_t ob = ((size_t)h * N + qh * 64) * 64;
#pragma unroll
  for (int n = 0; n < 8; ++n) {
    int d = n * 16 + lr;
#pragma unroll
    for (int r = 0; r < 4; ++r) {
      int qw = wave * 16 + lg * 4 + r;
      int kw = qw + 63 - d;
      if ((unsigned)kw < 64u) rwg[ob + (size_t)qw * 64 + kw] = f2bf(acc[n][r]);
    }
  }
}

// ---------------------------------------------------------------------------
// K3: flash attention v2.  Block = (h, qt).  Static softmax (no max track),
// deferred l-sum, double-buffered K/V via global_load_lds + XOR swizzle.
// Emits split-bf16 A' = [Ohi | Ohi | Olo]  ([4096][2304]).
// LDS: K0 @0, K1 @8192, V0 @16384, V1 @24576, PS @32768(9216), RH @41984(8192)
// ---------------------------------------------------------------------------
__global__ __launch_bounds__(256) void k_flash(const short* __restrict__ qg,
                                               const short* __restrict__ kg,
                                               const short* __restrict__ vTg,
                                               const short* __restrict__ rhTg,
                                               const short* __restrict__ rwg,
                                               short* __restrict__ aprime) {
  __shared__ __align__(16) char lds[50176];
  const int tid = threadIdx.x;
  const int wave = tid >> 6, lane = tid & 63, lr = lane & 15, lg = lane >> 4;
  const int h = blockIdx.x >> 6, qt = blockIdx.x & 63;

  // q fragments in registers for the whole kernel
  const size_t qrow = (size_t)h * N + qt * 64 + wave * 16 + lr;
  const s16x8 qa0 = *reinterpret_cast<const s16x8*>(qg + qrow * 64 + lg * 8);
  const s16x8 qa1 = *reinterpret_cast<const s16x8*>(qg + qrow * 64 + 32 + lg * 8);

  // rel_w preload: [n][r]
  const size_t rbase = ((size_t)(h * 64 + qt)) * 4096;
  float rw[4][4];
#pragma unroll
  for (int n = 0; n < 4; ++n)
#pragma unroll
    for (int r = 0; r < 4; ++r)
      rw[n][r] = bf2f(rwg[rbase + (size_t)(wave * 16 + lg * 4 + r) * 64 + n * 16 + lr]);

  // stage rhT slab (8KB) once
  short* RH = (short*)(lds + 41984);
  {
    const s16x8* src = reinterpret_cast<const s16x8*>(rhTg + rbase);
    s16x8* dst = reinterpret_cast<s16x8*>(RH);
    dst[tid] = src[tid];
    dst[tid + 256] = src[tid + 256];
  }

  // staging source offsets (inverse-swizzled), 2 chunks per thread per tile
  const int c0 = wave * 64 + lane, c1 = c0 + 256;
  const int r0 = c0 >> 3, r1 = c1 >> 3;
  const int sw0 = (((c0 & 7) << 4) ^ ((r0 & 7) << 4));
  const int sw1 = (((c1 & 7) << 4) ^ ((r1 & 7) << 4));
  const char* kgb = (const char*)kg + (size_t)h * N * 128;
  const char* vgb = (const char*)vTg + (size_t)h * 64 * 8192;
  const size_t ko0 = (size_t)r0 * 128 + sw0, ko1 = (size_t)r1 * 128 + sw1;
  const size_t vo0 = (size_t)r0 * 8192 + sw0, vo1 = (size_t)r1 * 8192 + sw1;
  char* lk0 = lds + wave * 1024;
  char* lv0 = lds + 16384 + wave * 1024;

  auto STAGE = [&](int t, int buf) {
    const char* kp = kgb + (size_t)t * 8192;
    const char* vp = vgb + (size_t)t * 128;
    char* lk = lk0 + buf * 8192;
    char* lv = lv0 + buf * 8192;
    gload16(kp + ko0, lk);
    gload16(kp + ko1, lk + 4096);
    gload16(vp + vo0, lv);
    gload16(vp + vo1, lv + 4096);
  };

  // swizzled read bases
  const int swz = (lr & 7) << 4;
  const int kb = lr * 128 + ((lg * 16) ^ swz);  // +n*2048, ^(ks2<<6), +buf*8192
  short* PS = (short*)(lds + 32768);
  const int ps_w = (wave * 16 + lg * 4) * 72 + lr;  // + r*72 + n*16
  const int ps_r = (wave * 16 + lr) * 72;           // + ks2*32 + lg*8

  f32x4 acc[4] = {};
  float lsum[4] = {0.f, 0.f, 0.f, 0.f};

  STAGE(0, 0);
  __syncthreads();

  for (int t = 0; t < 64; ++t) {
    const int buf = t & 1;
    STAGE(t + 1 < 64 ? t + 1 : 63, buf ^ 1);

    // QK^T
    const char* LK = lds + buf * 8192;
    f32x4 sa[4] = {};
#pragma unroll
    for (int ks2 = 0; ks2 < 2; ++ks2) {
      const s16x8 aq = ks2 ? qa1 : qa0;
#pragma unroll
      for (int n = 0; n < 4; ++n) {
        s16x8 b = *reinterpret_cast<const s16x8*>(LK + ((kb + n * 2048) ^ (ks2 << 6)));
        sa[n] = __builtin_amdgcn_mfma_f32_16x16x32_bf16(aq, b, sa[n], 0, 0, 0);
      }
    }

    // bias + static softmax (no max), pack P to LDS
    s16x4 rh4 = *reinterpret_cast<const s16x4*>(RH + t * 64 + wave * 16 + lg * 4);
    float rr[4];
#pragma unroll
    for (int r = 0; r < 4; ++r) rr[r] = bf2f(rh4[r]);
#pragma unroll
    for (int n = 0; n < 4; ++n) {
      float p0 = __expf(fmaf(sa[n][0], SCALE, rr[0] + rw[n][0]));
      float p1 = __expf(fmaf(sa[n][1], SCALE, rr[1] + rw[n][1]));
      float p2 = __expf(fmaf(sa[n][2], SCALE, rr[2] + rw[n][2]));
      float p3 = __expf(fmaf(sa[n][3], SCALE, rr[3] + rw[n][3]));
      lsum[0] += p0; lsum[1] += p1; lsum[2] += p2; lsum[3] += p3;
      unsigned pk01 = cvt_pk_bf16(p0, p1);
      unsigned pk23 = cvt_pk_bf16(p2, p3);
      PS[ps_w + n * 16] = (short)pk01;
      PS[ps_w + 72 + n * 16] = (short)(pk01 >> 16);
      PS[ps_w + 144 + n * 16] = (short)pk23;
      PS[ps_w + 216 + n * 16] = (short)(pk23 >> 16);
    }

    // O += P.V
    const char* LV = lds + 16384 + buf * 8192;
#pragma unroll
    for (int ks2 = 0; ks2 < 2; ++ks2) {
      s16x8 pa = *reinterpret_cast<const s16x8*>(PS + ps_r + ks2 * 32 + lg * 8);
#pragma unroll
      for (int n = 0; n < 4; ++n) {
        s16x8 b = *reinterpret_cast<const s16x8*>(LV + ((kb + n * 2048) ^ (ks2 << 6)));
        acc[n] = __builtin_amdgcn_mfma_f32_16x16x32_bf16(pa, b, acc[n], 0, 0, 0);
      }
    }
    __syncthreads();
  }

  // final l reduce over the 16 lanes of each row group
#pragma unroll
  for (int mask = 1; mask < 16; mask <<= 1)
#pragma unroll
    for (int r = 0; r < 4; ++r) lsum[r] += __shfl_xor(lsum[r], mask);

  const int orow = qt * 64 + wave * 16 + lg * 4;
#pragma unroll
  for (int r = 0; r < 4; ++r) {
    float inv = 1.0f / lsum[r];
#pragma unroll
    for (int n = 0; n < 4; ++n) {
      float o = acc[n][r] * inv;
      short hi = f2bf(o);
      float lo = o - bf2f(hi);
      size_t base = (size_t)(orow + r) * 2304 + h * 64 + n * 16 + lr;
      aprime[base] = hi;
      aprime[base + 768] = hi;
      aprime[base + 1536] = f2bf(lo);
    }
  }
}

// ---------------------------------------------------------------------------
extern "C" void kernel_launch(void* const* d_in, const int* in_sizes, int n_in,
                              void* d_out, int out_size, void* d_ws, size_t ws_size,
                              hipStream_t stream) {
  const float* x      = (const float*)d_in[0];
  const float* w_qkv  = (const float*)d_in[1];
  const float* b_qkv  = (const float*)d_in[2];
  const float* lora_A = (const float*)d_in[3];
  const float* lora_B = (const float*)d_in[4];
  const float* w_proj = (const float*)d_in[5];
  const float* b_proj = (const float*)d_in[6];
  const float* rel_h  = (const float*)d_in[7];
  const float* rel_w  = (const float*)d_in[8];
  float* out = (float*)d_out;

  char* ws = (char*)d_ws;
  // region A (reused): weff+xb+vg first, then aprime (all dead by flash)
  short* weff   = (short*)(ws + 0);           // 3,538,944 B
  short* xb     = (short*)(ws + 3538944);     // 6,291,456 B
  short* vg     = (short*)(ws + 9830400);     // 6,291,456 B  (ends 16,121,856)
  short* aprime = (short*)(ws + 0);           // 18,874,368 B (overlays the above)
  short* qg     = (short*)(ws + 18874368);    // 6,291,456
  short* kg     = (short*)(ws + 25165824);    // 6,291,456
  short* vTg    = (short*)(ws + 31457280);    // 6,291,456
  short* rhT    = (short*)(ws + 37748736);    // 6,291,456
  short* rwg    = (short*)(ws + 44040192);    // 6,291,456
  short* wsp    = (short*)(ws + 50331648);    // 3,538,944  -> total 53,870,592
  (void)ws_size; (void)in_sizes; (void)n_in; (void)out_size;

  k_weff<<<dim3((QKV * DIM + 255) / 256), dim3(256), 0, stream>>>(w_qkv, lora_A, lora_B, weff);
  k_x2bf<<<dim3(3072), dim3(256), 0, stream>>>(x, xb);
  k_wsplit<<<dim3(9, 768), dim3(256), 0, stream>>>(w_proj, wsp);
  k_gemm<12, 0><<<dim3(32, 18), dim3(256), 0, stream>>>(xb, weff, b_qkv, qg, kg, vg, nullptr);
  k_vT<<<dim3(64, NH), dim3(256), 0, stream>>>(vg, vTg);
  k_relh<<<dim3(NH * 64), dim3(256), 0, stream>>>(qg, rel_h, rhT);
  k_relw<<<dim3(NH * 64), dim3(256), 0, stream>>>(qg, rel_w, rwg);
  k_flash<<<dim3(NH * 64), dim3(256), 0, stream>>>(qg, kg, vTg, rhT, rwg, aprime);
  k_gemm<36, 1><<<dim3(32, 6), dim3(256), 0, stream>>>(aprime, wsp, b_proj, nullptr, nullptr, nullptr, out);
}

// Round 3
// 182.994 us; speedup vs baseline: 2.2658x; 1.1421x over previous
//
#include <hip/hip_runtime.h>
#include <stdint.h>

// ---------------------------------------------------------------------------
// Fused SAM-style attention block on MI355X (gfx950).  Round 3.
// Flash attn rebuilt on mfma_32x32x16: swapped QK^T (S^T lane-local per q),
// in-register P via cvt_pk + permlane32_swap, static softmax, exp2, dbuf K/V
// via global_load_lds + XOR swizzle.  Proj GEMM re-tiled 64x128 for occupancy.
// ---------------------------------------------------------------------------

typedef __attribute__((ext_vector_type(4))) float f32x4;
typedef __attribute__((ext_vector_type(16))) float f32x16;
typedef __attribute__((ext_vector_type(4))) float fvec4;
typedef __attribute__((ext_vector_type(8))) short s16x8;
typedef __attribute__((ext_vector_type(4))) short s16x4;
typedef __attribute__((ext_vector_type(4))) unsigned u32x4;

constexpr int NH  = 12;
constexpr int HD  = 64;
constexpr int DIM = 768;
constexpr int N   = 4096;
constexpr int QKV = 2304;
constexpr float LOG2E  = 1.4426950408889634f;
constexpr float SCALE2 = 0.125f * LOG2E;   // SCALE * log2(e)

static __device__ __forceinline__ short f2bf(float f) {
  unsigned u = __builtin_bit_cast(unsigned, f);
  unsigned r = (u + 0x7FFFu + ((u >> 16) & 1u)) >> 16;  // RNE
  return (short)r;
}
static __device__ __forceinline__ float bf2f(short s) {
  unsigned u = ((unsigned)(unsigned short)s) << 16;
  return __builtin_bit_cast(float, u);
}
static __device__ __forceinline__ unsigned cvt_pk_bf16(float a, float b) {
  unsigned r;
  asm("v_cvt_pk_bf16_f32 %0, %1, %2" : "=v"(r) : "v"(a), "v"(b));
  return r;
}
static __device__ __forceinline__ float ex2(float x) {
  float r;
  asm("v_exp_f32 %0, %1" : "=v"(r) : "v"(x));
  return r;
}
static __device__ __forceinline__ void gload16(const void* g, void* l) {
  __builtin_amdgcn_global_load_lds(
      (const __attribute__((address_space(1))) void*)g,
      (__attribute__((address_space(3))) void*)l, 16, 0, 0);
}

// ---------------------------------------------------------------------------
// K0: W_eff = w_qkv + lora_B @ lora_A  (bf16 out, [2304][768])
// ---------------------------------------------------------------------------
__global__ __launch_bounds__(256) void k_weff(const float* __restrict__ w_qkv,
                                              const float* __restrict__ lora_A,
                                              const float* __restrict__ lora_B,
                                              short* __restrict__ weff) {
  int e = blockIdx.x * 256 + threadIdx.x;
  if (e >= QKV * DIM) return;
  int r = e / DIM, c = e % DIM;
  float acc = w_qkv[e];
#pragma unroll
  for (int t = 0; t < 12; ++t) acc += lora_B[r * 12 + t] * lora_A[t * DIM + c];
  weff[e] = f2bf(acc);
}

// ---------------------------------------------------------------------------
// K0b: x fp32 -> bf16
// ---------------------------------------------------------------------------
__global__ __launch_bounds__(256) void k_x2bf(const float* __restrict__ x,
                                              short* __restrict__ xb) {
  int i = blockIdx.x * 256 + threadIdx.x;
  fvec4 v = *reinterpret_cast<const fvec4*>(x + (size_t)i * 4);
  s16x4 p;
  p[0] = f2bf(v[0]); p[1] = f2bf(v[1]); p[2] = f2bf(v[2]); p[3] = f2bf(v[3]);
  *reinterpret_cast<s16x4*>(xb + (size_t)i * 4) = p;
}

// ---------------------------------------------------------------------------
// K0c: w_proj -> split-bf16 B' [768][2304] = [Whi | Wlo | Whi]
// ---------------------------------------------------------------------------
__global__ __launch_bounds__(256) void k_wsplit(const float* __restrict__ w,
                                                short* __restrict__ ws) {
  int r = blockIdx.y;
  int kk = blockIdx.x * 256 + threadIdx.x;
  int blk = (kk >= 1536) ? 2 : (kk >= 768 ? 1 : 0);
  int c = kk - blk * 768;
  float wv = w[(size_t)r * 768 + c];
  short hi = f2bf(wv);
  ws[(size_t)r * 2304 + kk] = (blk == 1) ? f2bf(wv - bf2f(hi)) : hi;
}

// ---------------------------------------------------------------------------
// BMx128 MFMA GEMM, BK=64 (m97 structure).  A [M][K], B [Ncols][K] bf16.
// BM=128: 4 waves 2x2 over 64x64.  BM=64: 4 waves 2x2 over 32x64.
// MODE 0: qkv scatter epilogue.  MODE 1: fp32 out + bias.
// ---------------------------------------------------------------------------
template <int KIT, int MODE, int BM>
__global__ __launch_bounds__(256) void k_gemm(const short* __restrict__ A,
                                              const short* __restrict__ B,
                                              const float* __restrict__ bias,
                                              short* __restrict__ qo,
                                              short* __restrict__ ko,
                                              short* __restrict__ vo,
                                              float* __restrict__ outf) {
  constexpr int MFR = BM / 32;  // A m-frags per wave
  __shared__ __align__(16) char lds[BM * 128 + 16384];
  const int tid = threadIdx.x;
  const int wave = tid >> 6, lane = tid & 63, lr = lane & 15, lg = lane >> 4;
  const int wr = wave >> 1, wc = wave & 1;
  const int i0 = blockIdx.x * BM, j0 = blockIdx.y * 128;
  const int LDA = KIT * 128;  // row bytes

  size_t offA[MFR], offB[4];
#pragma unroll
  for (int it = 0; it < MFR; ++it) {
    int c = it * 256 + tid;
    int row = c >> 3;
    offA[it] = (size_t)row * LDA + (((c & 7) << 4) ^ ((row & 7) << 4));
  }
#pragma unroll
  for (int it = 0; it < 4; ++it) {
    int c = it * 256 + tid;
    int row = c >> 3;
    offB[it] = (size_t)row * LDA + (((c & 7) << 4) ^ ((row & 7) << 4));
  }
  const char* Ab = (const char*)A + (size_t)i0 * LDA;
  const char* Bb = (const char*)B + (size_t)j0 * LDA;
  char* la = lds + wave * 1024;
  char* lb = lds + BM * 128 + wave * 1024;

  const int swz = (lr & 7) << 4;
  const int ab = (wr * (BM / 2) + lr) * 128 + ((lg * 16) ^ swz);
  const int bb = BM * 128 + (wc * 64 + lr) * 128 + ((lg * 16) ^ swz);

  f32x4 acc[MFR][4] = {};

  for (int kt = 0; kt < KIT; ++kt) {
    const size_t kadd = (size_t)kt * 128;
#pragma unroll
    for (int it = 0; it < MFR; ++it) gload16(Ab + kadd + offA[it], la + it * 4096);
#pragma unroll
    for (int it = 0; it < 4; ++it) gload16(Bb + kadd + offB[it], lb + it * 4096);
    __syncthreads();
#pragma unroll
    for (int ks2 = 0; ks2 < 2; ++ks2) {
      s16x8 af[MFR], bf_[4];
#pragma unroll
      for (int m = 0; m < MFR; ++m)
        af[m] = *reinterpret_cast<const s16x8*>(lds + ((ab + m * 2048) ^ (ks2 << 6)));
#pragma unroll
      for (int n = 0; n < 4; ++n)
        bf_[n] = *reinterpret_cast<const s16x8*>(lds + ((bb + n * 2048) ^ (ks2 << 6)));
#pragma unroll
      for (int m = 0; m < MFR; ++m)
#pragma unroll
        for (int n = 0; n < 4; ++n)
          acc[m][n] = __builtin_amdgcn_mfma_f32_16x16x32_bf16(af[m], bf_[n], acc[m][n], 0, 0, 0);
    }
    __syncthreads();
  }

  if constexpr (MODE == 0) {
    const int three = j0 / 768;
    const int head = ((j0 % 768) >> 6) + wc;
    short* dst = (three == 0) ? qo : ((three == 1) ? ko : vo);
#pragma unroll
    for (int n = 0; n < 4; ++n) {
      const int col = n * 16 + lr;
      const float bj = bias[j0 + wc * 64 + col];
#pragma unroll
      for (int m = 0; m < MFR; ++m)
#pragma unroll
        for (int r = 0; r < 4; ++r) {
          int i = i0 + wr * (BM / 2) + m * 16 + lg * 4 + r;
          dst[((size_t)head * N + i) * HD + col] = f2bf(acc[m][n][r] + bj);
        }
    }
  } else {
#pragma unroll
    for (int n = 0; n < 4; ++n) {
      const int j = j0 + wc * 64 + n * 16 + lr;
      const float bj = bias[j];
#pragma unroll
      for (int m = 0; m < MFR; ++m)
#pragma unroll
        for (int r = 0; r < 4; ++r) {
          int i = i0 + wr * (BM / 2) + m * 16 + lg * 4 + r;
          outf[(size_t)i * 768 + j] = acc[m][n][r] + bj;
        }
    }
  }
}

// ---------------------------------------------------------------------------
// K1b: vT[h][c][i] = v[h][i][c]
// ---------------------------------------------------------------------------
__global__ __launch_bounds__(256) void k_vT(const short* __restrict__ vg,
                                            short* __restrict__ vTg) {
  __shared__ short ts[64 * 72];
  const int tid = threadIdx.x;
  const int i0 = blockIdx.x * 64;
  const int h = blockIdx.y;
#pragma unroll
  for (int it = 0; it < 2; ++it) {
    int ch = tid + 256 * it;
    int row = ch >> 3, cc = (ch & 7) * 8;
    *reinterpret_cast<s16x8*>(&ts[row * 72 + cc]) =
        *reinterpret_cast<const s16x8*>(&vg[((size_t)h * N + i0 + row) * HD + cc]);
  }
  __syncthreads();
#pragma unroll
  for (int it = 0; it < 2; ++it) {
    int ch = tid + 256 * it;
    int c = ch >> 3, ii = (ch & 7) * 8;
    s16x8 o;
#pragma unroll
    for (int j = 0; j < 8; ++j) o[j] = ts[(ii + j) * 72 + c];
    *reinterpret_cast<s16x8*>(&vTg[((size_t)h * HD + c) * N + i0 + ii]) = o;
  }
}

// ---------------------------------------------------------------------------
// K2a: rel_h via MFMA, stored TRANSPOSED: rhT[h][qh][kh][qw]
// ---------------------------------------------------------------------------
__global__ __launch_bounds__(256) void k_relh(const short* __restrict__ qg,
                                              const float* __restrict__ tab,
                                              short* __restrict__ rhT) {
  __shared__ short Ts[64 * 72];
  const int tid = threadIdx.x;
  const int wave = tid >> 6, lane = tid & 63, lr = lane & 15, lg = lane >> 4;
  const int h = blockIdx.x >> 6, qh = blockIdx.x & 63;
#pragma unroll
  for (int it = 0; it < 4; ++it) {
    int e = tid + 256 * it;
    int row = e >> 4, c4 = (e & 15) * 4;  // row = kh
    fvec4 v = *reinterpret_cast<const fvec4*>(tab + (size_t)(qh + 63 - row) * 64 + c4);
    s16x4 p;
    p[0] = f2bf(v[0]); p[1] = f2bf(v[1]); p[2] = f2bf(v[2]); p[3] = f2bf(v[3]);
    *reinterpret_cast<s16x4*>(&Ts[row * 72 + c4]) = p;
  }
  __syncthreads();
  const size_t qrow = (size_t)h * N + qh * 64 + wave * 16 + lr;
  const s16x8 a0 = *reinterpret_cast<const s16x8*>(qg + qrow * 64 + lg * 8);
  const s16x8 a1 = *reinterpret_cast<const s16x8*>(qg + qrow * 64 + 32 + lg * 8);
  f32x4 acc[4] = {};
#pragma unroll
  for (int ks2 = 0; ks2 < 2; ++ks2)
#pragma unroll
    for (int n = 0; n < 4; ++n) {
      s16x8 b = *reinterpret_cast<const s16x8*>(&Ts[(n * 16 + lr) * 72 + ks2 * 32 + lg * 8]);
      acc[n] = __builtin_amdgcn_mfma_f32_16x16x32_bf16(ks2 ? a1 : a0, b, acc[n], 0, 0, 0);
    }
  const size_t ob = ((size_t)(h * 64 + qh)) * 4096;
#pragma unroll
  for (int n = 0; n < 4; ++n) {
    s16x4 o;
#pragma unroll
    for (int r = 0; r < 4; ++r) o[r] = f2bf(acc[n][r]);
    *reinterpret_cast<s16x4*>(&rhT[ob + (size_t)(n * 16 + lr) * 64 + wave * 16 + lg * 4]) = o;
  }
}

// ---------------------------------------------------------------------------
// K2b: rel_w via U-GEMM + scatter.
// ---------------------------------------------------------------------------
__global__ __launch_bounds__(256) void k_relw(const short* __restrict__ qg,
                                              const float* __restrict__ tab,
                                              short* __restrict__ rwg) {
  __shared__ short Ts[128 * 72];
  const int tid = threadIdx.x;
  const int wave = tid >> 6, lane = tid & 63, lr = lane & 15, lg = lane >> 4;
  const int h = blockIdx.x >> 6, qh = blockIdx.x & 63;
#pragma unroll
  for (int it = 0; it < 8; ++it) {
    int e = tid + 256 * it;
    int row = e >> 4, c4 = (e & 15) * 4;  // row = d
    s16x4 p = {0, 0, 0, 0};
    if (row < 127) {
      fvec4 v = *reinterpret_cast<const fvec4*>(tab + (size_t)row * 64 + c4);
      p[0] = f2bf(v[0]); p[1] = f2bf(v[1]); p[2] = f2bf(v[2]); p[3] = f2bf(v[3]);
    }
    *reinterpret_cast<s16x4*>(&Ts[row * 72 + c4]) = p;
  }
  __syncthreads();
  const size_t qrow = (size_t)h * N + qh * 64 + wave * 16 + lr;
  const s16x8 a0 = *reinterpret_cast<const s16x8*>(qg + qrow * 64 + lg * 8);
  const s16x8 a1 = *reinterpret_cast<const s16x8*>(qg + qrow * 64 + 32 + lg * 8);
  f32x4 acc[8] = {};
#pragma unroll
  for (int ks2 = 0; ks2 < 2; ++ks2)
#pragma unroll
    for (int n = 0; n < 8; ++n) {
      s16x8 b = *reinterpret_cast<const s16x8*>(&Ts[(n * 16 + lr) * 72 + ks2 * 32 + lg * 8]);
      acc[n] = __builtin_amdgcn_mfma_f32_16x16x32_bf16(ks2 ? a1 : a0, b, acc[n], 0, 0, 0);
    }
  const size_t ob = ((size_t)h * N + qh * 64) * 64;
#pragma unroll
  for (int n = 0; n < 8; ++n) {
    int d = n * 16 + lr;
#pragma unroll
    for (int r = 0; r < 4; ++r) {
      int qw = wave * 16 + lg * 4 + r;
      int kw = qw + 63 - d;
      if ((unsigned)kw < 64u) rwg[ob + (size_t)qw * 64 + kw] = f2bf(acc[n][r]);
    }
  }
}

// ---------------------------------------------------------------------------
// K3: flash attention v3 (32x32 MFMA).  Block = (h, qt: 64 q rows).
// Wave (qh2, kh2) owns q-half 32 x k-half 32 of each 64-key tile.
// Swapped QK^T: S^T = K.Q^T -> lane holds 16 S for ONE q row (q = lane&31).
// P never touches LDS: cvt_pk_bf16 + permlane32_swap -> PV A-fragments.
// Static softmax (exp2, log2e folded), deferred l, cross-wave O/l reduce.
// LDS: K dbuf @0 (16KB), V dbuf @16384 (16KB); epilogue reuses as O/l scratch.
// ---------------------------------------------------------------------------
__global__ __launch_bounds__(256, 3) void k_flash(const short* __restrict__ qg,
                                                  const short* __restrict__ kg,
                                                  const short* __restrict__ vTg,
                                                  const short* __restrict__ rhTg,
                                                  const short* __restrict__ rwg,
                                                  short* __restrict__ aprime) {
  __shared__ __align__(16) char lds[32768];
  const int tid = threadIdx.x;
  const int wave = tid >> 6, lane = tid & 63;
  const int ql = lane & 31, hi = lane >> 5;
  const int qh2 = wave >> 1, kh2 = wave & 1;
  const int h = blockIdx.x >> 6, qt = blockIdx.x & 63;
  const int i0 = qt * 64;
  const int qglob = i0 + qh2 * 32 + ql;

  // Q fragments (B operand): qb[c] = Q[qglob][c*16 + hi*8 .. +8]
  const short* qrowp = qg + ((size_t)h * N + qglob) * 64 + hi * 8;
  const s16x8 qb0 = *reinterpret_cast<const s16x8*>(qrowp);
  const s16x8 qb1 = *reinterpret_cast<const s16x8*>(qrowp + 16);
  const s16x8 qb2 = *reinterpret_cast<const s16x8*>(qrowp + 32);
  const s16x8 qb3 = *reinterpret_cast<const s16x8*>(qrowp + 48);

  // rw2[reg] = log2e * rel_w[qglob][k],  k = kh2*32 + (reg&3) + 8*(reg>>2) + 4*hi
  const short* rwp = rwg + ((size_t)h * N + qglob) * 64 + kh2 * 32 + hi * 4;
  float rw2[16];
#pragma unroll
  for (int reg = 0; reg < 16; ++reg)
    rw2[reg] = LOG2E * bf2f(rwp[(reg & 3) + 8 * (reg >> 2)]);

  const short* rhp = rhTg + ((size_t)(h * 64 + qt)) * 4096 + qh2 * 32 + ql;

  // staging (as r2): K tile rows 0..63 (128B), V^T tile c-rows 0..63 (128B)
  const int c0 = wave * 64 + lane, c1 = c0 + 256;
  const int r0 = c0 >> 3, r1 = c1 >> 3;
  const int sw0 = (((c0 & 7) << 4) ^ ((r0 & 7) << 4));
  const int sw1 = (((c1 & 7) << 4) ^ ((r1 & 7) << 4));
  const char* kgb = (const char*)kg + (size_t)h * N * 128;
  const char* vgb = (const char*)vTg + (size_t)h * 64 * 8192;
  const size_t ko0 = (size_t)r0 * 128 + sw0, ko1 = (size_t)r1 * 128 + sw1;
  const size_t vo0 = (size_t)r0 * 8192 + sw0, vo1 = (size_t)r1 * 8192 + sw1;
  char* lk0 = lds + wave * 1024;
  char* lv0 = lds + 16384 + wave * 1024;

  auto STAGE = [&](int t, int buf) {
    const char* kp = kgb + (size_t)t * 8192;
    const char* vp = vgb + (size_t)t * 128;
    char* lk = lk0 + buf * 8192;
    char* lv = lv0 + buf * 8192;
    gload16(kp + ko0, lk);
    gload16(kp + ko1, lk + 4096);
    gload16(vp + vo0, lv);
    gload16(vp + vo1, lv + 4096);
  };

  // swizzled read bases (row&7 == ql&7 for all rows used)
  const int swz = (ql & 7) << 4;
  const int colb = (hi << 4) ^ swz;
  const int krd = (kh2 * 32 + ql) * 128;  // + (colb ^ (c<<5)), + buf*8192

  f32x16 acc0 = {}, acc1 = {};
  float lsum = 0.f;

  STAGE(0, 0);
  __syncthreads();

  for (int t = 0; t < 64; ++t) {
    const int buf = t & 1;
    STAGE(t + 1 < 64 ? t + 1 : 63, buf ^ 1);
    const float rh2 = LOG2E * bf2f(rhp[t * 64]);

    // QK^T (swapped): sa[reg] = S[k][q],  k = kh2*32 + (reg&3)+8*(reg>>2)+4*hi
    f32x16 sa = {};
    {
      const char* LK = lds + buf * 8192 + krd;
      s16x8 ka0 = *reinterpret_cast<const s16x8*>(LK + (colb ^ 0));
      sa = __builtin_amdgcn_mfma_f32_32x32x16_bf16(ka0, qb0, sa, 0, 0, 0);
      s16x8 ka1 = *reinterpret_cast<const s16x8*>(LK + (colb ^ 32));
      sa = __builtin_amdgcn_mfma_f32_32x32x16_bf16(ka1, qb1, sa, 0, 0, 0);
      s16x8 ka2 = *reinterpret_cast<const s16x8*>(LK + (colb ^ 64));
      sa = __builtin_amdgcn_mfma_f32_32x32x16_bf16(ka2, qb2, sa, 0, 0, 0);
      s16x8 ka3 = *reinterpret_cast<const s16x8*>(LK + (colb ^ 96));
      sa = __builtin_amdgcn_mfma_f32_32x32x16_bf16(ka3, qb3, sa, 0, 0, 0);
    }

    // static softmax in-register
    float p[16];
#pragma unroll
    for (int reg = 0; reg < 16; ++reg) {
      p[reg] = ex2(fmaf(sa[reg], SCALE2, rh2 + rw2[reg]));
      lsum += p[reg];
    }

    // P -> PV A-fragments: W[c][j]=cvt_pk(p[4c+2j],p[4c+2j+1]);
    // swap32(W[c0][j], W[c0+1][j]) -> words (j, j+2) of pa[kcl], c0=2*kcl.
    unsigned w00 = cvt_pk_bf16(p[0], p[1]),   w01 = cvt_pk_bf16(p[2], p[3]);
    unsigned w10 = cvt_pk_bf16(p[4], p[5]),   w11 = cvt_pk_bf16(p[6], p[7]);
    unsigned w20 = cvt_pk_bf16(p[8], p[9]),   w21 = cvt_pk_bf16(p[10], p[11]);
    unsigned w30 = cvt_pk_bf16(p[12], p[13]), w31 = cvt_pk_bf16(p[14], p[15]);
    asm("v_permlane32_swap_b32 %0, %1" : "+v"(w00), "+v"(w10));
    asm("v_permlane32_swap_b32 %0, %1" : "+v"(w01), "+v"(w11));
    asm("v_permlane32_swap_b32 %0, %1" : "+v"(w20), "+v"(w30));
    asm("v_permlane32_swap_b32 %0, %1" : "+v"(w21), "+v"(w31));
    u32x4 u0 = {w00, w01, w10, w11};
    u32x4 u1 = {w20, w21, w30, w31};
    s16x8 pa0 = __builtin_bit_cast(s16x8, u0);
    s16x8 pa1 = __builtin_bit_cast(s16x8, u1);

    // PV: acc[ct] += P[q][k-half] . V[k][ct*32+ql]
    {
      const char* LV = lds + 16384 + buf * 8192;
      const int cv0 = (kh2 * 2 + 0) << 5, cv1 = (kh2 * 2 + 1) << 5;
      s16x8 v00 = *reinterpret_cast<const s16x8*>(LV + ql * 128 + (colb ^ cv0));
      acc0 = __builtin_amdgcn_mfma_f32_32x32x16_bf16(pa0, v00, acc0, 0, 0, 0);
      s16x8 v01 = *reinterpret_cast<const s16x8*>(LV + ql * 128 + (colb ^ cv1));
      acc0 = __builtin_amdgcn_mfma_f32_32x32x16_bf16(pa1, v01, acc0, 0, 0, 0);
      s16x8 v10 = *reinterpret_cast<const s16x8*>(LV + 4096 + ql * 128 + (colb ^ cv0));
      acc1 = __builtin_amdgcn_mfma_f32_32x32x16_bf16(pa0, v10, acc1, 0, 0, 0);
      s16x8 v11 = *reinterpret_cast<const s16x8*>(LV + 4096 + ql * 128 + (colb ^ cv1));
      acc1 = __builtin_amdgcn_mfma_f32_32x32x16_bf16(pa1, v11, acc1, 0, 0, 0);
    }
    __syncthreads();
  }

  // ---- epilogue: cross-wave (k-half) reduction of l and O ----
  lsum += __shfl_xor(lsum, 32);             // per-q over hi halves
  float* LS = (float*)(lds + 16384);        // [qh2][kh2][32]
  float* OF = (float*)lds;                  // [qh2][qoff 32][c 64] fp32 (16KB)
  if (lane < 32) LS[(qh2 * 2 + kh2) * 32 + ql] = lsum;
  if (kh2 == 0) {
#pragma unroll
    for (int reg = 0; reg < 16; ++reg) {
      int qoff = (reg & 3) + 8 * (reg >> 2) + 4 * hi;
      OF[qh2 * 2048 + qoff * 64 + ql] = acc0[reg];
      OF[qh2 * 2048 + qoff * 64 + 32 + ql] = acc1[reg];
    }
  }
  __syncthreads();
  if (kh2 == 1) {
    float invq = 1.0f / (LS[qh2 * 64 + ql] + LS[qh2 * 64 + 32 + ql]);
#pragma unroll
    for (int reg = 0; reg < 16; ++reg) {
      int qoff = (reg & 3) + 8 * (reg >> 2) + 4 * hi;
      float inv = __shfl(invq, qoff);
      size_t rbase = (size_t)(i0 + qh2 * 32 + qoff) * 2304 + h * 64;
#pragma unroll
      for (int ct = 0; ct < 2; ++ct) {
        float o = ((ct ? acc1 : acc0)[reg] + OF[qh2 * 2048 + qoff * 64 + ct * 32 + ql]) * inv;
        short ohi = f2bf(o);
        float lo = o - bf2f(ohi);
        size_t base = rbase + ct * 32 + ql;
        aprime[base] = ohi;
        aprime[base + 768] = ohi;
        aprime[base + 1536] = f2bf(lo);
      }
    }
  }
}

// ---------------------------------------------------------------------------
extern "C" void kernel_launch(void* const* d_in, const int* in_sizes, int n_in,
                              void* d_out, int out_size, void* d_ws, size_t ws_size,
                              hipStream_t stream) {
  const float* x      = (const float*)d_in[0];
  const float* w_qkv  = (const float*)d_in[1];
  const float* b_qkv  = (const float*)d_in[2];
  const float* lora_A = (const float*)d_in[3];
  const float* lora_B = (const float*)d_in[4];
  const float* w_proj = (const float*)d_in[5];
  const float* b_proj = (const float*)d_in[6];
  const float* rel_h  = (const float*)d_in[7];
  const float* rel_w  = (const float*)d_in[8];
  float* out = (float*)d_out;

  char* ws = (char*)d_ws;
  short* weff   = (short*)(ws + 0);           // 3,538,944 B (dead before flash)
  short* xb     = (short*)(ws + 3538944);     // 6,291,456 B (dead before flash)
  short* vg     = (short*)(ws + 9830400);     // 6,291,456 B (dead before flash)
  short* aprime = (short*)(ws + 0);           // 18,874,368 B (overlays the above)
  short* qg     = (short*)(ws + 18874368);
  short* kg     = (short*)(ws + 25165824);
  short* vTg    = (short*)(ws + 31457280);
  short* rhT    = (short*)(ws + 37748736);
  short* rwg    = (short*)(ws + 44040192);
  short* wsp    = (short*)(ws + 50331648);    // -> total 53,870,592
  (void)ws_size; (void)in_sizes; (void)n_in; (void)out_size;

  k_weff<<<dim3((QKV * DIM + 255) / 256), dim3(256), 0, stream>>>(w_qkv, lora_A, lora_B, weff);
  k_x2bf<<<dim3(3072), dim3(256), 0, stream>>>(x, xb);
  k_wsplit<<<dim3(9, 768), dim3(256), 0, stream>>>(w_proj, wsp);
  k_gemm<12, 0, 128><<<dim3(32, 18), dim3(256), 0, stream>>>(xb, weff, b_qkv, qg, kg, vg, nullptr);
  k_vT<<<dim3(64, NH), dim3(256), 0, stream>>>(vg, vTg);
  k_relh<<<dim3(NH * 64), dim3(256), 0, stream>>>(qg, rel_h, rhT);
  k_relw<<<dim3(NH * 64), dim3(256), 0, stream>>>(qg, rel_w, rwg);
  k_flash<<<dim3(NH * 64), dim3(256), 0, stream>>>(qg, kg, vTg, rhT, rwg, aprime);
  k_gemm<36, 1, 64><<<dim3(64, 6), dim3(256), 0, stream>>>(aprime, wsp, b_proj, nullptr, nullptr, nullptr, out);
}

// Round 4
// 179.808 us; speedup vs baseline: 2.3059x; 1.0177x over previous
//
#include <hip/hip_runtime.h>
#include <stdint.h>

// ---------------------------------------------------------------------------
// Fused SAM-style attention block on MI355X (gfx950).  Round 4.
// Flash attn: waves = (kt2, kh2) over a 128-key double tile, q=64 rows/wave in
// registers -> 1.0x LDS amplification (was 2.0x).  Static softmax, in-register
// P (cvt_pk + permlane32_swap), gload16 staging w/ XOR swizzle, cross-wave
// O/l reduction epilogue, XCD-swizzled block ids.
// ---------------------------------------------------------------------------

typedef __attribute__((ext_vector_type(4))) float f32x4;
typedef __attribute__((ext_vector_type(16))) float f32x16;
typedef __attribute__((ext_vector_type(4))) float fvec4;
typedef __attribute__((ext_vector_type(8))) short s16x8;
typedef __attribute__((ext_vector_type(4))) short s16x4;
typedef __attribute__((ext_vector_type(4))) unsigned u32x4;

constexpr int NH  = 12;
constexpr int HD  = 64;
constexpr int DIM = 768;
constexpr int N   = 4096;
constexpr int QKV = 2304;
constexpr float LOG2E  = 1.4426950408889634f;
constexpr float SCALE2 = 0.125f * LOG2E;   // SCALE * log2(e)

static __device__ __forceinline__ short f2bf(float f) {
  unsigned u = __builtin_bit_cast(unsigned, f);
  unsigned r = (u + 0x7FFFu + ((u >> 16) & 1u)) >> 16;  // RNE
  return (short)r;
}
static __device__ __forceinline__ float bf2f(short s) {
  unsigned u = ((unsigned)(unsigned short)s) << 16;
  return __builtin_bit_cast(float, u);
}
static __device__ __forceinline__ unsigned cvt_pk_bf16(float a, float b) {
  unsigned r;
  asm("v_cvt_pk_bf16_f32 %0, %1, %2" : "=v"(r) : "v"(a), "v"(b));
  return r;
}
static __device__ __forceinline__ float ex2(float x) {
  float r;
  asm("v_exp_f32 %0, %1" : "=v"(r) : "v"(x));
  return r;
}
static __device__ __forceinline__ void gload16(const void* g, void* l) {
  __builtin_amdgcn_global_load_lds(
      (const __attribute__((address_space(1))) void*)g,
      (__attribute__((address_space(3))) void*)l, 16, 0, 0);
}

// ---------------------------------------------------------------------------
// K0: W_eff = w_qkv + lora_B @ lora_A  (bf16 out, [2304][768])
// ---------------------------------------------------------------------------
__global__ __launch_bounds__(256) void k_weff(const float* __restrict__ w_qkv,
                                              const float* __restrict__ lora_A,
                                              const float* __restrict__ lora_B,
                                              short* __restrict__ weff) {
  int e = blockIdx.x * 256 + threadIdx.x;
  if (e >= QKV * DIM) return;
  int r = e / DIM, c = e % DIM;
  float acc = w_qkv[e];
#pragma unroll
  for (int t = 0; t < 12; ++t) acc += lora_B[r * 12 + t] * lora_A[t * DIM + c];
  weff[e] = f2bf(acc);
}

// ---------------------------------------------------------------------------
// K0b: x fp32 -> bf16
// ---------------------------------------------------------------------------
__global__ __launch_bounds__(256) void k_x2bf(const float* __restrict__ x,
                                              short* __restrict__ xb) {
  int i = blockIdx.x * 256 + threadIdx.x;
  fvec4 v = *reinterpret_cast<const fvec4*>(x + (size_t)i * 4);
  s16x4 p;
  p[0] = f2bf(v[0]); p[1] = f2bf(v[1]); p[2] = f2bf(v[2]); p[3] = f2bf(v[3]);
  *reinterpret_cast<s16x4*>(xb + (size_t)i * 4) = p;
}

// ---------------------------------------------------------------------------
// K0c: w_proj -> split-bf16 B' [768][2304] = [Whi | Wlo | Whi]
// ---------------------------------------------------------------------------
__global__ __launch_bounds__(256) void k_wsplit(const float* __restrict__ w,
                                                short* __restrict__ ws) {
  int r = blockIdx.y;
  int kk = blockIdx.x * 256 + threadIdx.x;
  int blk = (kk >= 1536) ? 2 : (kk >= 768 ? 1 : 0);
  int c = kk - blk * 768;
  float wv = w[(size_t)r * 768 + c];
  short hi = f2bf(wv);
  ws[(size_t)r * 2304 + kk] = (blk == 1) ? f2bf(wv - bf2f(hi)) : hi;
}

// ---------------------------------------------------------------------------
// BMx128 MFMA GEMM, BK=64 (m97 structure).  A [M][K], B [Ncols][K] bf16.
// MODE 0: qkv scatter epilogue.  MODE 1: fp32 out + bias.
// ---------------------------------------------------------------------------
template <int KIT, int MODE, int BM>
__global__ __launch_bounds__(256) void k_gemm(const short* __restrict__ A,
                                              const short* __restrict__ B,
                                              const float* __restrict__ bias,
                                              short* __restrict__ qo,
                                              short* __restrict__ ko,
                                              short* __restrict__ vo,
                                              float* __restrict__ outf) {
  constexpr int MFR = BM / 32;  // A m-frags per wave
  __shared__ __align__(16) char lds[BM * 128 + 16384];
  const int tid = threadIdx.x;
  const int wave = tid >> 6, lane = tid & 63, lr = lane & 15, lg = lane >> 4;
  const int wr = wave >> 1, wc = wave & 1;
  const int i0 = blockIdx.x * BM, j0 = blockIdx.y * 128;
  const int LDA = KIT * 128;  // row bytes

  size_t offA[MFR], offB[4];
#pragma unroll
  for (int it = 0; it < MFR; ++it) {
    int c = it * 256 + tid;
    int row = c >> 3;
    offA[it] = (size_t)row * LDA + (((c & 7) << 4) ^ ((row & 7) << 4));
  }
#pragma unroll
  for (int it = 0; it < 4; ++it) {
    int c = it * 256 + tid;
    int row = c >> 3;
    offB[it] = (size_t)row * LDA + (((c & 7) << 4) ^ ((row & 7) << 4));
  }
  const char* Ab = (const char*)A + (size_t)i0 * LDA;
  const char* Bb = (const char*)B + (size_t)j0 * LDA;
  char* la = lds + wave * 1024;
  char* lb = lds + BM * 128 + wave * 1024;

  const int swz = (lr & 7) << 4;
  const int ab = (wr * (BM / 2) + lr) * 128 + ((lg * 16) ^ swz);
  const int bb = BM * 128 + (wc * 64 + lr) * 128 + ((lg * 16) ^ swz);

  f32x4 acc[MFR][4] = {};

  for (int kt = 0; kt < KIT; ++kt) {
    const size_t kadd = (size_t)kt * 128;
#pragma unroll
    for (int it = 0; it < MFR; ++it) gload16(Ab + kadd + offA[it], la + it * 4096);
#pragma unroll
    for (int it = 0; it < 4; ++it) gload16(Bb + kadd + offB[it], lb + it * 4096);
    __syncthreads();
#pragma unroll
    for (int ks2 = 0; ks2 < 2; ++ks2) {
      s16x8 af[MFR], bf_[4];
#pragma unroll
      for (int m = 0; m < MFR; ++m)
        af[m] = *reinterpret_cast<const s16x8*>(lds + ((ab + m * 2048) ^ (ks2 << 6)));
#pragma unroll
      for (int n = 0; n < 4; ++n)
        bf_[n] = *reinterpret_cast<const s16x8*>(lds + ((bb + n * 2048) ^ (ks2 << 6)));
#pragma unroll
      for (int m = 0; m < MFR; ++m)
#pragma unroll
        for (int n = 0; n < 4; ++n)
          acc[m][n] = __builtin_amdgcn_mfma_f32_16x16x32_bf16(af[m], bf_[n], acc[m][n], 0, 0, 0);
    }
    __syncthreads();
  }

  if constexpr (MODE == 0) {
    const int three = j0 / 768;
    const int head = ((j0 % 768) >> 6) + wc;
    short* dst = (three == 0) ? qo : ((three == 1) ? ko : vo);
#pragma unroll
    for (int n = 0; n < 4; ++n) {
      const int col = n * 16 + lr;
      const float bj = bias[j0 + wc * 64 + col];
#pragma unroll
      for (int m = 0; m < MFR; ++m)
#pragma unroll
        for (int r = 0; r < 4; ++r) {
          int i = i0 + wr * (BM / 2) + m * 16 + lg * 4 + r;
          dst[((size_t)head * N + i) * HD + col] = f2bf(acc[m][n][r] + bj);
        }
    }
  } else {
#pragma unroll
    for (int n = 0; n < 4; ++n) {
      const int j = j0 + wc * 64 + n * 16 + lr;
      const float bj = bias[j];
#pragma unroll
      for (int m = 0; m < MFR; ++m)
#pragma unroll
        for (int r = 0; r < 4; ++r) {
          int i = i0 + wr * (BM / 2) + m * 16 + lg * 4 + r;
          outf[(size_t)i * 768 + j] = acc[m][n][r] + bj;
        }
    }
  }
}

// ---------------------------------------------------------------------------
// K1b: vT[h][c][i] = v[h][i][c]
// ---------------------------------------------------------------------------
__global__ __launch_bounds__(256) void k_vT(const short* __restrict__ vg,
                                            short* __restrict__ vTg) {
  __shared__ short ts[64 * 72];
  const int tid = threadIdx.x;
  const int i0 = blockIdx.x * 64;
  const int h = blockIdx.y;
#pragma unroll
  for (int it = 0; it < 2; ++it) {
    int ch = tid + 256 * it;
    int row = ch >> 3, cc = (ch & 7) * 8;
    *reinterpret_cast<s16x8*>(&ts[row * 72 + cc]) =
        *reinterpret_cast<const s16x8*>(&vg[((size_t)h * N + i0 + row) * HD + cc]);
  }
  __syncthreads();
#pragma unroll
  for (int it = 0; it < 2; ++it) {
    int ch = tid + 256 * it;
    int c = ch >> 3, ii = (ch & 7) * 8;
    s16x8 o;
#pragma unroll
    for (int j = 0; j < 8; ++j) o[j] = ts[(ii + j) * 72 + c];
    *reinterpret_cast<s16x8*>(&vTg[((size_t)h * HD + c) * N + i0 + ii]) = o;
  }
}

// ---------------------------------------------------------------------------
// K2a: rel_h via MFMA, stored TRANSPOSED: rhT[h][qh][kh][qw]
// ---------------------------------------------------------------------------
__global__ __launch_bounds__(256) void k_relh(const short* __restrict__ qg,
                                              const float* __restrict__ tab,
                                              short* __restrict__ rhT) {
  __shared__ short Ts[64 * 72];
  const int tid = threadIdx.x;
  const int wave = tid >> 6, lane = tid & 63, lr = lane & 15, lg = lane >> 4;
  const int h = blockIdx.x >> 6, qh = blockIdx.x & 63;
#pragma unroll
  for (int it = 0; it < 4; ++it) {
    int e = tid + 256 * it;
    int row = e >> 4, c4 = (e & 15) * 4;  // row = kh
    fvec4 v = *reinterpret_cast<const fvec4*>(tab + (size_t)(qh + 63 - row) * 64 + c4);
    s16x4 p;
    p[0] = f2bf(v[0]); p[1] = f2bf(v[1]); p[2] = f2bf(v[2]); p[3] = f2bf(v[3]);
    *reinterpret_cast<s16x4*>(&Ts[row * 72 + c4]) = p;
  }
  __syncthreads();
  const size_t qrow = (size_t)h * N + qh * 64 + wave * 16 + lr;
  const s16x8 a0 = *reinterpret_cast<const s16x8*>(qg + qrow * 64 + lg * 8);
  const s16x8 a1 = *reinterpret_cast<const s16x8*>(qg + qrow * 64 + 32 + lg * 8);
  f32x4 acc[4] = {};
#pragma unroll
  for (int ks2 = 0; ks2 < 2; ++ks2)
#pragma unroll
    for (int n = 0; n < 4; ++n) {
      s16x8 b = *reinterpret_cast<const s16x8*>(&Ts[(n * 16 + lr) * 72 + ks2 * 32 + lg * 8]);
      acc[n] = __builtin_amdgcn_mfma_f32_16x16x32_bf16(ks2 ? a1 : a0, b, acc[n], 0, 0, 0);
    }
  const size_t ob = ((size_t)(h * 64 + qh)) * 4096;
#pragma unroll
  for (int n = 0; n < 4; ++n) {
    s16x4 o;
#pragma unroll
    for (int r = 0; r < 4; ++r) o[r] = f2bf(acc[n][r]);
    *reinterpret_cast<s16x4*>(&rhT[ob + (size_t)(n * 16 + lr) * 64 + wave * 16 + lg * 4]) = o;
  }
}

// ---------------------------------------------------------------------------
// K2b: rel_w via U-GEMM + scatter.
// ---------------------------------------------------------------------------
__global__ __launch_bounds__(256) void k_relw(const short* __restrict__ qg,
                                              const float* __restrict__ tab,
                                              short* __restrict__ rwg) {
  __shared__ short Ts[128 * 72];
  const int tid = threadIdx.x;
  const int wave = tid >> 6, lane = tid & 63, lr = lane & 15, lg = lane >> 4;
  const int h = blockIdx.x >> 6, qh = blockIdx.x & 63;
#pragma unroll
  for (int it = 0; it < 8; ++it) {
    int e = tid + 256 * it;
    int row = e >> 4, c4 = (e & 15) * 4;  // row = d
    s16x4 p = {0, 0, 0, 0};
    if (row < 127) {
      fvec4 v = *reinterpret_cast<const fvec4*>(tab + (size_t)row * 64 + c4);
      p[0] = f2bf(v[0]); p[1] = f2bf(v[1]); p[2] = f2bf(v[2]); p[3] = f2bf(v[3]);
    }
    *reinterpret_cast<s16x4*>(&Ts[row * 72 + c4]) = p;
  }
  __syncthreads();
  const size_t qrow = (size_t)h * N + qh * 64 + wave * 16 + lr;
  const s16x8 a0 = *reinterpret_cast<const s16x8*>(qg + qrow * 64 + lg * 8);
  const s16x8 a1 = *reinterpret_cast<const s16x8*>(qg + qrow * 64 + 32 + lg * 8);
  f32x4 acc[8] = {};
#pragma unroll
  for (int ks2 = 0; ks2 < 2; ++ks2)
#pragma unroll
    for (int n = 0; n < 8; ++n) {
      s16x8 b = *reinterpret_cast<const s16x8*>(&Ts[(n * 16 + lr) * 72 + ks2 * 32 + lg * 8]);
      acc[n] = __builtin_amdgcn_mfma_f32_16x16x32_bf16(ks2 ? a1 : a0, b, acc[n], 0, 0, 0);
    }
  const size_t ob = ((size_t)h * N + qh * 64) * 64;
#pragma unroll
  for (int n = 0; n < 8; ++n) {
    int d = n * 16 + lr;
#pragma unroll
    for (int r = 0; r < 4; ++r) {
      int qw = wave * 16 + lg * 4 + r;
      int kw = qw + 63 - d;
      if ((unsigned)kw < 64u) rwg[ob + (size_t)qw * 64 + kw] = f2bf(acc[n][r]);
    }
  }
}

// ---------------------------------------------------------------------------
// K3: flash attention v4.  Block = (h, qt: 64 q rows), 4 waves = (kt2, kh2)
// over a 128-key double tile; each wave owns a disjoint 32-key slice and all
// 64 q rows (Q in registers).  Per iter: stage next 128-key K/V double tile,
// 8 ds_read_b128, 16 MFMA, static softmax, in-register P.
// LDS: dbuf 2 x { K[128][128B] @0, V[2][64][128B] @16K } = 64KB.
// Epilogue: cross-wave l and O reduction through LDS, split-bf16 A' out.
// ---------------------------------------------------------------------------
#define QG_BLOCK(QB0, QB1, QB2, QB3, RW, RH2, ACC0, ACC1, LA, LB)              \
  do {                                                                         \
    f32x16 sa = {};                                                            \
    __builtin_amdgcn_s_setprio(1);                                             \
    sa = __builtin_amdgcn_mfma_f32_32x32x16_bf16(kf0, QB0, sa, 0, 0, 0);       \
    sa = __builtin_amdgcn_mfma_f32_32x32x16_bf16(kf1, QB1, sa, 0, 0, 0);       \
    sa = __builtin_amdgcn_mfma_f32_32x32x16_bf16(kf2, QB2, sa, 0, 0, 0);       \
    sa = __builtin_amdgcn_mfma_f32_32x32x16_bf16(kf3, QB3, sa, 0, 0, 0);       \
    __builtin_amdgcn_s_setprio(0);                                             \
    float p[16];                                                               \
    _Pragma("unroll")                                                          \
    for (int reg = 0; reg < 16; ++reg)                                         \
      p[reg] = ex2(fmaf(sa[reg], SCALE2, RH2 + RW[reg]));                      \
    float t0 = (p[0] + p[1]) + (p[2] + p[3]);                                  \
    float t1 = (p[4] + p[5]) + (p[6] + p[7]);                                  \
    float t2 = (p[8] + p[9]) + (p[10] + p[11]);                                \
    float t3 = (p[12] + p[13]) + (p[14] + p[15]);                              \
    LA += t0 + t1;                                                             \
    LB += t2 + t3;                                                             \
    unsigned w00 = cvt_pk_bf16(p[0], p[1]),   w01 = cvt_pk_bf16(p[2], p[3]);   \
    unsigned w10 = cvt_pk_bf16(p[4], p[5]),   w11 = cvt_pk_bf16(p[6], p[7]);   \
    unsigned w20 = cvt_pk_bf16(p[8], p[9]),   w21 = cvt_pk_bf16(p[10], p[11]); \
    unsigned w30 = cvt_pk_bf16(p[12], p[13]), w31 = cvt_pk_bf16(p[14], p[15]); \
    asm("v_permlane32_swap_b32 %0, %1" : "+v"(w00), "+v"(w10));                \
    asm("v_permlane32_swap_b32 %0, %1" : "+v"(w01), "+v"(w11));                \
    asm("v_permlane32_swap_b32 %0, %1" : "+v"(w20), "+v"(w30));                \
    asm("v_permlane32_swap_b32 %0, %1" : "+v"(w21), "+v"(w31));                \
    u32x4 u0 = {w00, w01, w10, w11};                                           \
    u32x4 u1 = {w20, w21, w30, w31};                                           \
    s16x8 pa0 = __builtin_bit_cast(s16x8, u0);                                 \
    s16x8 pa1 = __builtin_bit_cast(s16x8, u1);                                 \
    __builtin_amdgcn_s_setprio(1);                                             \
    ACC0 = __builtin_amdgcn_mfma_f32_32x32x16_bf16(pa0, vf0, ACC0, 0, 0, 0);   \
    ACC0 = __builtin_amdgcn_mfma_f32_32x32x16_bf16(pa1, vf2, ACC0, 0, 0, 0);   \
    ACC1 = __builtin_amdgcn_mfma_f32_32x32x16_bf16(pa0, vf1, ACC1, 0, 0, 0);   \
    ACC1 = __builtin_amdgcn_mfma_f32_32x32x16_bf16(pa1, vf3, ACC1, 0, 0, 0);   \
    __builtin_amdgcn_s_setprio(0);                                             \
  } while (0)

__global__ __launch_bounds__(256, 2) void k_flash(const short* __restrict__ qg,
                                                  const short* __restrict__ kg,
                                                  const short* __restrict__ vTg,
                                                  const short* __restrict__ rhTg,
                                                  const short* __restrict__ rwg,
                                                  short* __restrict__ aprime) {
  __shared__ __align__(16) char lds[65536];
  const int tid = threadIdx.x;
  const int wave = tid >> 6, lane = tid & 63;
  const int ql = lane & 31, hi = lane >> 5;
  const int kt2 = wave & 1, kh2 = wave >> 1;
  const int bid = blockIdx.x;
  const int id = (bid & 7) * 96 + (bid >> 3);  // bijective XCD swizzle (768%8==0)
  const int h = id >> 6, qt = id & 63;
  const int i0 = qt * 64;

  // Q fragments in registers: qbG C = Q[i0 + G*32 + ql][C*16 + hi*8 .. +8]
  const short* q0p = qg + ((size_t)h * N + i0 + ql) * 64 + hi * 8;
  const short* q1p = q0p + 32 * 64;
  const s16x8 qb00 = *reinterpret_cast<const s16x8*>(q0p);
  const s16x8 qb01 = *reinterpret_cast<const s16x8*>(q0p + 16);
  const s16x8 qb02 = *reinterpret_cast<const s16x8*>(q0p + 32);
  const s16x8 qb03 = *reinterpret_cast<const s16x8*>(q0p + 48);
  const s16x8 qb10 = *reinterpret_cast<const s16x8*>(q1p);
  const s16x8 qb11 = *reinterpret_cast<const s16x8*>(q1p + 16);
  const s16x8 qb12 = *reinterpret_cast<const s16x8*>(q1p + 32);
  const s16x8 qb13 = *reinterpret_cast<const s16x8*>(q1p + 48);

  // rel_w preload (tile-invariant): rw[qg][reg], k = kh2*32 + (reg&3)+8*(reg>>2)+4*hi
  f32x16 rw0, rw1;
  {
    const short* rwp0 = rwg + ((size_t)h * N + i0 + ql) * 64 + kh2 * 32 + hi * 4;
    const short* rwp1 = rwp0 + 32 * 64;
#pragma unroll
    for (int reg = 0; reg < 16; ++reg) {
      int o = (reg & 3) + 8 * (reg >> 2);
      rw0[reg] = LOG2E * bf2f(rwp0[o]);
      rw1[reg] = LOG2E * bf2f(rwp1[o]);
    }
  }
  const short* rhp = rhTg + ((size_t)(h * 64 + qt)) * 4096;

  // staging offsets (inverse-swizzled).  wave 0/1: K rows wave*64..+64;
  // wave 2/3: V tile (wave-2), c-rows 0..63.
  int soff[8];
  const char* sbase;
  if (wave < 2) {
    sbase = (const char*)kg + (size_t)h * N * 128 + wave * 64 * 128;
#pragma unroll
    for (int it = 0; it < 8; ++it) {
      int c = it * 64 + lane, row = c >> 3;
      soff[it] = row * 128 + (((c & 7) << 4) ^ ((row & 7) << 4));
    }
  } else {
    sbase = (const char*)vTg + (size_t)h * 64 * 8192 + (wave - 2) * 128;
#pragma unroll
    for (int it = 0; it < 8; ++it) {
      int c = it * 64 + lane, r = c >> 3;
      soff[it] = r * 8192 + (((c & 7) << 4) ^ ((r & 7) << 4));
    }
  }
  const int sstep = (wave < 2) ? 16384 : 256;
  char* lreg = lds + wave * 8192;

  auto STAGE = [&](int i, int buf) {
    const char* sp = sbase + (size_t)i * sstep;
    char* lp = lreg + buf * 32768;
#pragma unroll
    for (int it = 0; it < 8; ++it) gload16(sp + soff[it], lp + it * 1024);
  };

  // fragment read offsets (within a buffer)
  const int swzq = (ql & 7) << 4;
  const int krow = (kt2 * 64 + kh2 * 32 + ql) * 128;
  const int kco0 = krow + ((0 * 32 + hi * 16) ^ swzq);
  const int kco1 = krow + ((1 * 32 + hi * 16) ^ swzq);
  const int kco2 = krow + ((2 * 32 + hi * 16) ^ swzq);
  const int kco3 = krow + ((3 * 32 + hi * 16) ^ swzq);
  const int vrow0 = 16384 + kt2 * 8192 + ql * 128;          // ct=0
  const int vrow1 = vrow0 + 32 * 128;                       // ct=1
  const int vch0 = (kh2 * 64 + 0 * 32 + hi * 16) ^ swzq;    // ks=0
  const int vch1 = (kh2 * 64 + 1 * 32 + hi * 16) ^ swzq;    // ks=1
  const int vco0 = vrow0 + vch0;   // ks0 ct0
  const int vco1 = vrow1 + vch0;   // ks0 ct1
  const int vco2 = vrow0 + vch1;   // ks1 ct0
  const int vco3 = vrow1 + vch1;   // ks1 ct1

  f32x16 acc00 = {}, acc01 = {}, acc10 = {}, acc11 = {};
  float la0 = 0.f, lb0 = 0.f, la1 = 0.f, lb1 = 0.f;

  // rel_h prefetch (kh = i*2 + kt2)
  unsigned short rhc0 = (unsigned short)rhp[(size_t)kt2 * 64 + ql];
  unsigned short rhc1 = (unsigned short)rhp[(size_t)kt2 * 64 + 32 + ql];

  STAGE(0, 0);
  __syncthreads();

  for (int i = 0; i < 32; ++i) {
    const int buf = i & 1;
    if (i + 1 < 32) STAGE(i + 1, buf ^ 1);
    const int nx = (i + 1 < 32) ? i + 1 : 31;
    unsigned short rhn0 = (unsigned short)rhp[(size_t)(nx * 2 + kt2) * 64 + ql];
    unsigned short rhn1 = (unsigned short)rhp[(size_t)(nx * 2 + kt2) * 64 + 32 + ql];

    const char* bufp = lds + buf * 32768;
    s16x8 kf0 = *reinterpret_cast<const s16x8*>(bufp + kco0);
    s16x8 kf1 = *reinterpret_cast<const s16x8*>(bufp + kco1);
    s16x8 kf2 = *reinterpret_cast<const s16x8*>(bufp + kco2);
    s16x8 kf3 = *reinterpret_cast<const s16x8*>(bufp + kco3);
    s16x8 vf0 = *reinterpret_cast<const s16x8*>(bufp + vco0);
    s16x8 vf1 = *reinterpret_cast<const s16x8*>(bufp + vco1);
    s16x8 vf2 = *reinterpret_cast<const s16x8*>(bufp + vco2);
    s16x8 vf3 = *reinterpret_cast<const s16x8*>(bufp + vco3);

    const float rh20 = LOG2E * bf2f((short)rhc0);
    const float rh21 = LOG2E * bf2f((short)rhc1);

    QG_BLOCK(qb00, qb01, qb02, qb03, rw0, rh20, acc00, acc01, la0, lb0);
    QG_BLOCK(qb10, qb11, qb12, qb13, rw1, rh21, acc10, acc11, la1, lb1);

    rhc0 = rhn0; rhc1 = rhn1;
    __syncthreads();
  }

  // ---- epilogue: cross-wave reduction of l and O ----
  float l0 = la0 + lb0, l1 = la1 + lb1;
  l0 += __shfl_xor(l0, 32);
  l1 += __shfl_xor(l1, 32);
  float* LS = (float*)lds;               // [4 waves][64 q]
  if (lane < 32) {
    LS[wave * 64 + ql] = l0;
    LS[wave * 64 + 32 + ql] = l1;
  }
  __syncthreads();
  const int eq = wave * 16 + (lane >> 2);     // this thread's q row (epilogue)
  const int cb = (lane & 3) * 16;             // this thread's 16-col chunk
  float inv = 1.0f / (LS[eq] + LS[64 + eq] + LS[128 + eq] + LS[192 + eq]);
  __syncthreads();
  float* OF = (float*)lds;               // [4 waves][64 q][64 c], c XOR-swizzled
#pragma unroll
  for (int qg2 = 0; qg2 < 2; ++qg2)
#pragma unroll
    for (int ct = 0; ct < 2; ++ct) {
      const f32x16& a = qg2 ? (ct ? acc11 : acc10) : (ct ? acc01 : acc00);
#pragma unroll
      for (int reg = 0; reg < 16; ++reg) {
        int q = qg2 * 32 + (reg & 3) + 8 * (reg >> 2) + 4 * hi;
        int c = ct * 32 + ql;
        OF[wave * 4096 + q * 64 + (c ^ ((q & 7) << 2))] = a[reg];
      }
    }
  __syncthreads();
  f32x4 osum[4] = {};
#pragma unroll
  for (int w = 0; w < 4; ++w)
#pragma unroll
    for (int j = 0; j < 4; ++j)
      osum[j] += *reinterpret_cast<const f32x4*>(
          &OF[w * 4096 + eq * 64 + ((cb + j * 4) ^ ((eq & 7) << 2))]);

  s16x8 hi8[2], lo8[2];
#pragma unroll
  for (int j = 0; j < 4; ++j)
#pragma unroll
    for (int e = 0; e < 4; ++e) {
      float o = osum[j][e] * inv;
      short oh = f2bf(o);
      float lo = o - bf2f(oh);
      int idx = j * 4 + e;
      hi8[idx >> 3][idx & 7] = oh;
      lo8[idx >> 3][idx & 7] = f2bf(lo);
    }
  size_t obase = (size_t)(i0 + eq) * 2304 + h * 64 + cb;
  *reinterpret_cast<s16x8*>(&aprime[obase]) = hi8[0];
  *reinterpret_cast<s16x8*>(&aprime[obase + 8]) = hi8[1];
  *reinterpret_cast<s16x8*>(&aprime[obase + 768]) = hi8[0];
  *reinterpret_cast<s16x8*>(&aprime[obase + 776]) = hi8[1];
  *reinterpret_cast<s16x8*>(&aprime[obase + 1536]) = lo8[0];
  *reinterpret_cast<s16x8*>(&aprime[obase + 1544]) = lo8[1];
}

// ---------------------------------------------------------------------------
extern "C" void kernel_launch(void* const* d_in, const int* in_sizes, int n_in,
                              void* d_out, int out_size, void* d_ws, size_t ws_size,
                              hipStream_t stream) {
  const float* x      = (const float*)d_in[0];
  const float* w_qkv  = (const float*)d_in[1];
  const float* b_qkv  = (const float*)d_in[2];
  const float* lora_A = (const float*)d_in[3];
  const float* lora_B = (const float*)d_in[4];
  const float* w_proj = (const float*)d_in[5];
  const float* b_proj = (const float*)d_in[6];
  const float* rel_h  = (const float*)d_in[7];
  const float* rel_w  = (const float*)d_in[8];
  float* out = (float*)d_out;

  char* ws = (char*)d_ws;
  short* weff   = (short*)(ws + 0);           // dead before flash
  short* xb     = (short*)(ws + 3538944);     // dead before flash
  short* vg     = (short*)(ws + 9830400);     // dead before flash
  short* aprime = (short*)(ws + 0);           // overlays the above
  short* qg     = (short*)(ws + 18874368);
  short* kg     = (short*)(ws + 25165824);
  short* vTg    = (short*)(ws + 31457280);
  short* rhT    = (short*)(ws + 37748736);
  short* rwg    = (short*)(ws + 44040192);
  short* wsp    = (short*)(ws + 50331648);    // -> total 53,870,592
  (void)ws_size; (void)in_sizes; (void)n_in; (void)out_size;

  k_weff<<<dim3((QKV * DIM + 255) / 256), dim3(256), 0, stream>>>(w_qkv, lora_A, lora_B, weff);
  k_x2bf<<<dim3(3072), dim3(256), 0, stream>>>(x, xb);
  k_wsplit<<<dim3(9, 768), dim3(256), 0, stream>>>(w_proj, wsp);
  k_gemm<12, 0, 128><<<dim3(32, 18), dim3(256), 0, stream>>>(xb, weff, b_qkv, qg, kg, vg, nullptr);
  k_vT<<<dim3(64, NH), dim3(256), 0, stream>>>(vg, vTg);
  k_relh<<<dim3(NH * 64), dim3(256), 0, stream>>>(qg, rel_h, rhT);
  k_relw<<<dim3(NH * 64), dim3(256), 0, stream>>>(qg, rel_w, rwg);
  k_flash<<<dim3(NH * 64), dim3(256), 0, stream>>>(qg, kg, vTg, rhT, rwg, aprime);
  k_gemm<36, 1, 64><<<dim3(64, 6), dim3(256), 0, stream>>>(aprime, wsp, b_proj, nullptr, nullptr, nullptr, out);
}

// Round 5
// 171.225 us; speedup vs baseline: 2.4215x; 1.0501x over previous
//
#include <hip/hip_runtime.h>
#include <stdint.h>

// ---------------------------------------------------------------------------
// Fused SAM-style attention block on MI355X (gfx950).  Round 5.
// Key change vs r4: counted s_waitcnt vmcnt(N) + raw s_barrier (T3/T4) in
// flash AND both GEMMs -- __syncthreads() was draining all prefetch loads
// (compiler emits vmcnt(0) before s_barrier), killing the double buffer.
// ---------------------------------------------------------------------------

typedef __attribute__((ext_vector_type(4))) float f32x4;
typedef __attribute__((ext_vector_type(16))) float f32x16;
typedef __attribute__((ext_vector_type(4))) float fvec4;
typedef __attribute__((ext_vector_type(8))) short s16x8;
typedef __attribute__((ext_vector_type(4))) short s16x4;
typedef __attribute__((ext_vector_type(4))) unsigned u32x4;

constexpr int NH  = 12;
constexpr int HD  = 64;
constexpr int DIM = 768;
constexpr int N   = 4096;
constexpr int QKV = 2304;
constexpr float LOG2E  = 1.4426950408889634f;
constexpr float SCALE2 = 0.125f * LOG2E;   // SCALE * log2(e)

static __device__ __forceinline__ short f2bf(float f) {
  unsigned u = __builtin_bit_cast(unsigned, f);
  unsigned r = (u + 0x7FFFu + ((u >> 16) & 1u)) >> 16;  // RNE
  return (short)r;
}
static __device__ __forceinline__ float bf2f(short s) {
  unsigned u = ((unsigned)(unsigned short)s) << 16;
  return __builtin_bit_cast(float, u);
}
static __device__ __forceinline__ unsigned cvt_pk_bf16(float a, float b) {
  unsigned r;
  asm("v_cvt_pk_bf16_f32 %0, %1, %2" : "=v"(r) : "v"(a), "v"(b));
  return r;
}
static __device__ __forceinline__ float ex2(float x) {
  float r;
  asm("v_exp_f32 %0, %1" : "=v"(r) : "v"(x));
  return r;
}
static __device__ __forceinline__ void gload16(const void* g, void* l) {
  __builtin_amdgcn_global_load_lds(
      (const __attribute__((address_space(1))) void*)g,
      (__attribute__((address_space(3))) void*)l, 16, 0, 0);
}
static __device__ __forceinline__ void barrier_pre() {
  __builtin_amdgcn_s_barrier();
  __builtin_amdgcn_sched_barrier(0);
}
static __device__ __forceinline__ void barrier_post() {
  __builtin_amdgcn_sched_barrier(0);
  __builtin_amdgcn_s_barrier();
  __builtin_amdgcn_sched_barrier(0);
}

// ---------------------------------------------------------------------------
// K0: W_eff = w_qkv + lora_B @ lora_A  (bf16 out, [2304][768])
// ---------------------------------------------------------------------------
__global__ __launch_bounds__(256) void k_weff(const float* __restrict__ w_qkv,
                                              const float* __restrict__ lora_A,
                                              const float* __restrict__ lora_B,
                                              short* __restrict__ weff) {
  int e = blockIdx.x * 256 + threadIdx.x;
  if (e >= QKV * DIM) return;
  int r = e / DIM, c = e % DIM;
  float acc = w_qkv[e];
#pragma unroll
  for (int t = 0; t < 12; ++t) acc += lora_B[r * 12 + t] * lora_A[t * DIM + c];
  weff[e] = f2bf(acc);
}

// ---------------------------------------------------------------------------
// K0b: x fp32 -> bf16
// ---------------------------------------------------------------------------
__global__ __launch_bounds__(256) void k_x2bf(const float* __restrict__ x,
                                              short* __restrict__ xb) {
  int i = blockIdx.x * 256 + threadIdx.x;
  fvec4 v = *reinterpret_cast<const fvec4*>(x + (size_t)i * 4);
  s16x4 p;
  p[0] = f2bf(v[0]); p[1] = f2bf(v[1]); p[2] = f2bf(v[2]); p[3] = f2bf(v[3]);
  *reinterpret_cast<s16x4*>(xb + (size_t)i * 4) = p;
}

// ---------------------------------------------------------------------------
// K0c: w_proj -> split-bf16 B' [768][2304] = [Whi | Wlo | Whi]
// ---------------------------------------------------------------------------
__global__ __launch_bounds__(256) void k_wsplit(const float* __restrict__ w,
                                                short* __restrict__ ws) {
  int r = blockIdx.y;
  int kk = blockIdx.x * 256 + threadIdx.x;
  int blk = (kk >= 1536) ? 2 : (kk >= 768 ? 1 : 0);
  int c = kk - blk * 768;
  float wv = w[(size_t)r * 768 + c];
  short hi = f2bf(wv);
  ws[(size_t)r * 2304 + kk] = (blk == 1) ? f2bf(wv - bf2f(hi)) : hi;
}

// ---------------------------------------------------------------------------
// BMx128 MFMA GEMM, BK=64, DOUBLE-buffered with counted vmcnt + raw barriers.
// A [M][K], B [Ncols][K] bf16.  MODE 0: qkv scatter.  MODE 1: fp32 out+bias.
// ---------------------------------------------------------------------------
template <int KIT, int MODE, int BM>
__global__ __launch_bounds__(256, 2) void k_gemm(const short* __restrict__ A,
                                                 const short* __restrict__ B,
                                                 const float* __restrict__ bias,
                                                 short* __restrict__ qo,
                                                 short* __restrict__ ko,
                                                 short* __restrict__ vo,
                                                 float* __restrict__ outf) {
  constexpr int MFR = BM / 32;              // A m-frags per wave
  constexpr int BUFB = BM * 128 + 16384;    // bytes per buffer (A + B tiles)
  __shared__ __align__(16) char lds[2 * BUFB];
  const int tid = threadIdx.x;
  const int wave = tid >> 6, lane = tid & 63, lr = lane & 15, lg = lane >> 4;
  const int wr = wave >> 1, wc = wave & 1;
  const int i0 = blockIdx.x * BM, j0 = blockIdx.y * 128;
  const int LDA = KIT * 128;  // row bytes

  size_t offA[MFR], offB[4];
#pragma unroll
  for (int it = 0; it < MFR; ++it) {
    int c = it * 256 + tid;
    int row = c >> 3;
    offA[it] = (size_t)row * LDA + (((c & 7) << 4) ^ ((row & 7) << 4));
  }
#pragma unroll
  for (int it = 0; it < 4; ++it) {
    int c = it * 256 + tid;
    int row = c >> 3;
    offB[it] = (size_t)row * LDA + (((c & 7) << 4) ^ ((row & 7) << 4));
  }
  const char* Ab = (const char*)A + (size_t)i0 * LDA;
  const char* Bb = (const char*)B + (size_t)j0 * LDA;

  auto STAGE = [&](int kt, int b) {
    char* base = lds + b * BUFB;
    const size_t kadd = (size_t)kt * 128;
#pragma unroll
    for (int it = 0; it < MFR; ++it)
      gload16(Ab + kadd + offA[it], base + wave * 1024 + it * 4096);
#pragma unroll
    for (int it = 0; it < 4; ++it)
      gload16(Bb + kadd + offB[it], base + BM * 128 + wave * 1024 + it * 4096);
  };

  const int swz = (lr & 7) << 4;
  const int ab = (wr * (BM / 2) + lr) * 128 + ((lg * 16) ^ swz);
  const int bb = BM * 128 + (wc * 64 + lr) * 128 + ((lg * 16) ^ swz);

  f32x4 acc[MFR][4] = {};

  STAGE(0, 0);
  for (int kt = 0; kt < KIT; ++kt) {
    const int buf = kt & 1;
    if (kt + 1 < KIT) {
      STAGE(kt + 1, buf ^ 1);
      if constexpr (BM == 128)
        asm volatile("s_waitcnt vmcnt(8)" ::: "memory");
      else
        asm volatile("s_waitcnt vmcnt(6)" ::: "memory");
    } else {
      asm volatile("s_waitcnt vmcnt(0)" ::: "memory");
    }
    barrier_pre();
    const char* bufp = lds + buf * BUFB;
#pragma unroll
    for (int ks2 = 0; ks2 < 2; ++ks2) {
      s16x8 af[MFR], bf_[4];
#pragma unroll
      for (int m = 0; m < MFR; ++m)
        af[m] = *reinterpret_cast<const s16x8*>(bufp + ((ab + m * 2048) ^ (ks2 << 6)));
#pragma unroll
      for (int n = 0; n < 4; ++n)
        bf_[n] = *reinterpret_cast<const s16x8*>(bufp + ((bb + n * 2048) ^ (ks2 << 6)));
#pragma unroll
      for (int m = 0; m < MFR; ++m)
#pragma unroll
        for (int n = 0; n < 4; ++n)
          acc[m][n] = __builtin_amdgcn_mfma_f32_16x16x32_bf16(af[m], bf_[n], acc[m][n], 0, 0, 0);
    }
    barrier_post();
  }

  if constexpr (MODE == 0) {
    const int three = j0 / 768;
    const int head = ((j0 % 768) >> 6) + wc;
    short* dst = (three == 0) ? qo : ((three == 1) ? ko : vo);
#pragma unroll
    for (int n = 0; n < 4; ++n) {
      const int col = n * 16 + lr;
      const float bj = bias[j0 + wc * 64 + col];
#pragma unroll
      for (int m = 0; m < MFR; ++m)
#pragma unroll
        for (int r = 0; r < 4; ++r) {
          int i = i0 + wr * (BM / 2) + m * 16 + lg * 4 + r;
          dst[((size_t)head * N + i) * HD + col] = f2bf(acc[m][n][r] + bj);
        }
    }
  } else {
#pragma unroll
    for (int n = 0; n < 4; ++n) {
      const int j = j0 + wc * 64 + n * 16 + lr;
      const float bj = bias[j];
#pragma unroll
      for (int m = 0; m < MFR; ++m)
#pragma unroll
        for (int r = 0; r < 4; ++r) {
          int i = i0 + wr * (BM / 2) + m * 16 + lg * 4 + r;
          outf[(size_t)i * 768 + j] = acc[m][n][r] + bj;
        }
    }
  }
}

// ---------------------------------------------------------------------------
// K1b: vT[h][c][i] = v[h][i][c]
// ---------------------------------------------------------------------------
__global__ __launch_bounds__(256) void k_vT(const short* __restrict__ vg,
                                            short* __restrict__ vTg) {
  __shared__ short ts[64 * 72];
  const int tid = threadIdx.x;
  const int i0 = blockIdx.x * 64;
  const int h = blockIdx.y;
#pragma unroll
  for (int it = 0; it < 2; ++it) {
    int ch = tid + 256 * it;
    int row = ch >> 3, cc = (ch & 7) * 8;
    *reinterpret_cast<s16x8*>(&ts[row * 72 + cc]) =
        *reinterpret_cast<const s16x8*>(&vg[((size_t)h * N + i0 + row) * HD + cc]);
  }
  __syncthreads();
#pragma unroll
  for (int it = 0; it < 2; ++it) {
    int ch = tid + 256 * it;
    int c = ch >> 3, ii = (ch & 7) * 8;
    s16x8 o;
#pragma unroll
    for (int j = 0; j < 8; ++j) o[j] = ts[(ii + j) * 72 + c];
    *reinterpret_cast<s16x8*>(&vTg[((size_t)h * HD + c) * N + i0 + ii]) = o;
  }
}

// ---------------------------------------------------------------------------
// K2a: rel_h via MFMA, stored TRANSPOSED: rhT[h][qh][kh][qw]
// ---------------------------------------------------------------------------
__global__ __launch_bounds__(256) void k_relh(const short* __restrict__ qg,
                                              const float* __restrict__ tab,
                                              short* __restrict__ rhT) {
  __shared__ short Ts[64 * 72];
  const int tid = threadIdx.x;
  const int wave = tid >> 6, lane = tid & 63, lr = lane & 15, lg = lane >> 4;
  const int h = blockIdx.x >> 6, qh = blockIdx.x & 63;
#pragma unroll
  for (int it = 0; it < 4; ++it) {
    int e = tid + 256 * it;
    int row = e >> 4, c4 = (e & 15) * 4;  // row = kh
    fvec4 v = *reinterpret_cast<const fvec4*>(tab + (size_t)(qh + 63 - row) * 64 + c4);
    s16x4 p;
    p[0] = f2bf(v[0]); p[1] = f2bf(v[1]); p[2] = f2bf(v[2]); p[3] = f2bf(v[3]);
    *reinterpret_cast<s16x4*>(&Ts[row * 72 + c4]) = p;
  }
  __syncthreads();
  const size_t qrow = (size_t)h * N + qh * 64 + wave * 16 + lr;
  const s16x8 a0 = *reinterpret_cast<const s16x8*>(qg + qrow * 64 + lg * 8);
  const s16x8 a1 = *reinterpret_cast<const s16x8*>(qg + qrow * 64 + 32 + lg * 8);
  f32x4 acc[4] = {};
#pragma unroll
  for (int ks2 = 0; ks2 < 2; ++ks2)
#pragma unroll
    for (int n = 0; n < 4; ++n) {
      s16x8 b = *reinterpret_cast<const s16x8*>(&Ts[(n * 16 + lr) * 72 + ks2 * 32 + lg * 8]);
      acc[n] = __builtin_amdgcn_mfma_f32_16x16x32_bf16(ks2 ? a1 : a0, b, acc[n], 0, 0, 0);
    }
  const size_t ob = ((size_t)(h * 64 + qh)) * 4096;
#pragma unroll
  for (int n = 0; n < 4; ++n) {
    s16x4 o;
#pragma unroll
    for (int r = 0; r < 4; ++r) o[r] = f2bf(acc[n][r]);
    *reinterpret_cast<s16x4*>(&rhT[ob + (size_t)(n * 16 + lr) * 64 + wave * 16 + lg * 4]) = o;
  }
}

// ---------------------------------------------------------------------------
// K2b: rel_w via U-GEMM + scatter.
// ---------------------------------------------------------------------------
__global__ __launch_bounds__(256) void k_relw(const short* __restrict__ qg,
                                              const float* __restrict__ tab,
                                              short* __restrict__ rwg) {
  __shared__ short Ts[128 * 72];
  const int tid = threadIdx.x;
  const int wave = tid >> 6, lane = tid & 63, lr = lane & 15, lg = lane >> 4;
  const int h = blockIdx.x >> 6, qh = blockIdx.x & 63;
#pragma unroll
  for (int it = 0; it < 8; ++it) {
    int e = tid + 256 * it;
    int row = e >> 4, c4 = (e & 15) * 4;  // row = d
    s16x4 p = {0, 0, 0, 0};
    if (row < 127) {
      fvec4 v = *reinterpret_cast<const fvec4*>(tab + (size_t)row * 64 + c4);
      p[0] = f2bf(v[0]); p[1] = f2bf(v[1]); p[2] = f2bf(v[2]); p[3] = f2bf(v[3]);
    }
    *reinterpret_cast<s16x4*>(&Ts[row * 72 + c4]) = p;
  }
  __syncthreads();
  const size_t qrow = (size_t)h * N + qh * 64 + wave * 16 + lr;
  const s16x8 a0 = *reinterpret_cast<const s16x8*>(qg + qrow * 64 + lg * 8);
  const s16x8 a1 = *reinterpret_cast<const s16x8*>(qg + qrow * 64 + 32 + lg * 8);
  f32x4 acc[8] = {};
#pragma unroll
  for (int ks2 = 0; ks2 < 2; ++ks2)
#pragma unroll
    for (int n = 0; n < 8; ++n) {
      s16x8 b = *reinterpret_cast<const s16x8*>(&Ts[(n * 16 + lr) * 72 + ks2 * 32 + lg * 8]);
      acc[n] = __builtin_amdgcn_mfma_f32_16x16x32_bf16(ks2 ? a1 : a0, b, acc[n], 0, 0, 0);
    }
  const size_t ob = ((size_t)h * N + qh * 64) * 64;
#pragma unroll
  for (int n = 0; n < 8; ++n) {
    int d = n * 16 + lr;
#pragma unroll
    for (int r = 0; r < 4; ++r) {
      int qw = wave * 16 + lg * 4 + r;
      int kw = qw + 63 - d;
      if ((unsigned)kw < 64u) rwg[ob + (size_t)qw * 64 + kw] = f2bf(acc[n][r]);
    }
  }
}

// ---------------------------------------------------------------------------
// K3: flash attention v5.  Same decomposition as r4 (waves = (kt2,kh2) slices
// of a 128-key double tile, q=64/wave in regs), but pipelined with counted
// vmcnt + raw barriers so the K/V prefetch really overlaps compute.
// ---------------------------------------------------------------------------
#define QG_BLOCK(QB0, QB1, QB2, QB3, RW, RH2, ACC0, ACC1, LA, LB)              \
  do {                                                                         \
    f32x16 sa = {};                                                            \
    __builtin_amdgcn_s_setprio(1);                                             \
    sa = __builtin_amdgcn_mfma_f32_32x32x16_bf16(kf0, QB0, sa, 0, 0, 0);       \
    sa = __builtin_amdgcn_mfma_f32_32x32x16_bf16(kf1, QB1, sa, 0, 0, 0);       \
    sa = __builtin_amdgcn_mfma_f32_32x32x16_bf16(kf2, QB2, sa, 0, 0, 0);       \
    sa = __builtin_amdgcn_mfma_f32_32x32x16_bf16(kf3, QB3, sa, 0, 0, 0);       \
    __builtin_amdgcn_s_setprio(0);                                             \
    float p[16];                                                               \
    _Pragma("unroll")                                                          \
    for (int reg = 0; reg < 16; ++reg)                                         \
      p[reg] = ex2(fmaf(sa[reg], SCALE2, RH2 + RW[reg]));                      \
    float t0 = (p[0] + p[1]) + (p[2] + p[3]);                                  \
    float t1 = (p[4] + p[5]) + (p[6] + p[7]);                                  \
    float t2 = (p[8] + p[9]) + (p[10] + p[11]);                                \
    float t3 = (p[12] + p[13]) + (p[14] + p[15]);                              \
    LA += t0 + t1;                                                             \
    LB += t2 + t3;                                                             \
    unsigned w00 = cvt_pk_bf16(p[0], p[1]),   w01 = cvt_pk_bf16(p[2], p[3]);   \
    unsigned w10 = cvt_pk_bf16(p[4], p[5]),   w11 = cvt_pk_bf16(p[6], p[7]);   \
    unsigned w20 = cvt_pk_bf16(p[8], p[9]),   w21 = cvt_pk_bf16(p[10], p[11]); \
    unsigned w30 = cvt_pk_bf16(p[12], p[13]), w31 = cvt_pk_bf16(p[14], p[15]); \
    asm("v_permlane32_swap_b32 %0, %1" : "+v"(w00), "+v"(w10));                \
    asm("v_permlane32_swap_b32 %0, %1" : "+v"(w01), "+v"(w11));                \
    asm("v_permlane32_swap_b32 %0, %1" : "+v"(w20), "+v"(w30));                \
    asm("v_permlane32_swap_b32 %0, %1" : "+v"(w21), "+v"(w31));                \
    u32x4 u0 = {w00, w01, w10, w11};                                           \
    u32x4 u1 = {w20, w21, w30, w31};                                           \
    s16x8 pa0 = __builtin_bit_cast(s16x8, u0);                                 \
    s16x8 pa1 = __builtin_bit_cast(s16x8, u1);                                 \
    __builtin_amdgcn_s_setprio(1);                                             \
    ACC0 = __builtin_amdgcn_mfma_f32_32x32x16_bf16(pa0, vf0, ACC0, 0, 0, 0);   \
    ACC0 = __builtin_amdgcn_mfma_f32_32x32x16_bf16(pa1, vf2, ACC0, 0, 0, 0);   \
    ACC1 = __builtin_amdgcn_mfma_f32_32x32x16_bf16(pa0, vf1, ACC1, 0, 0, 0);   \
    ACC1 = __builtin_amdgcn_mfma_f32_32x32x16_bf16(pa1, vf3, ACC1, 0, 0, 0);   \
    __builtin_amdgcn_s_setprio(0);                                             \
  } while (0)

#define FLASH_BODY(BUFOFF, RHU0, RHU1)                                         \
  do {                                                                         \
    const char* bufp = lds + (BUFOFF);                                         \
    s16x8 kf0 = *reinterpret_cast<const s16x8*>(bufp + kco0);                  \
    s16x8 kf1 = *reinterpret_cast<const s16x8*>(bufp + kco1);                  \
    s16x8 kf2 = *reinterpret_cast<const s16x8*>(bufp + kco2);                  \
    s16x8 kf3 = *reinterpret_cast<const s16x8*>(bufp + kco3);                  \
    s16x8 vf0 = *reinterpret_cast<const s16x8*>(bufp + vco0);                  \
    s16x8 vf1 = *reinterpret_cast<const s16x8*>(bufp + vco1);                  \
    s16x8 vf2 = *reinterpret_cast<const s16x8*>(bufp + vco2);                  \
    s16x8 vf3 = *reinterpret_cast<const s16x8*>(bufp + vco3);                  \
    const float rh20 = LOG2E * bf2f((short)(RHU0));                            \
    const float rh21 = LOG2E * bf2f((short)(RHU1));                            \
    QG_BLOCK(qb00, qb01, qb02, qb03, rw0, rh20, acc00, acc01, la0, lb0);       \
    QG_BLOCK(qb10, qb11, qb12, qb13, rw1, rh21, acc10, acc11, la1, lb1);       \
  } while (0)

__global__ __launch_bounds__(256, 2) void k_flash(const short* __restrict__ qg,
                                                  const short* __restrict__ kg,
                                                  const short* __restrict__ vTg,
                                                  const short* __restrict__ rhTg,
                                                  const short* __restrict__ rwg,
                                                  short* __restrict__ aprime) {
  __shared__ __align__(16) char lds[65536];
  const int tid = threadIdx.x;
  const int wave = tid >> 6, lane = tid & 63;
  const int ql = lane & 31, hi = lane >> 5;
  const int kt2 = wave & 1, kh2 = wave >> 1;
  const int bid = blockIdx.x;
  const int id = (bid & 7) * 96 + (bid >> 3);  // bijective XCD swizzle (768%8==0)
  const int h = id >> 6, qt = id & 63;
  const int i0 = qt * 64;

  // Q fragments in registers: qbG C = Q[i0 + G*32 + ql][C*16 + hi*8 .. +8]
  const short* q0p = qg + ((size_t)h * N + i0 + ql) * 64 + hi * 8;
  const short* q1p = q0p + 32 * 64;
  const s16x8 qb00 = *reinterpret_cast<const s16x8*>(q0p);
  const s16x8 qb01 = *reinterpret_cast<const s16x8*>(q0p + 16);
  const s16x8 qb02 = *reinterpret_cast<const s16x8*>(q0p + 32);
  const s16x8 qb03 = *reinterpret_cast<const s16x8*>(q0p + 48);
  const s16x8 qb10 = *reinterpret_cast<const s16x8*>(q1p);
  const s16x8 qb11 = *reinterpret_cast<const s16x8*>(q1p + 16);
  const s16x8 qb12 = *reinterpret_cast<const s16x8*>(q1p + 32);
  const s16x8 qb13 = *reinterpret_cast<const s16x8*>(q1p + 48);

  // rel_w preload (tile-invariant)
  f32x16 rw0, rw1;
  {
    const short* rwp0 = rwg + ((size_t)h * N + i0 + ql) * 64 + kh2 * 32 + hi * 4;
    const short* rwp1 = rwp0 + 32 * 64;
#pragma unroll
    for (int reg = 0; reg < 16; ++reg) {
      int o = (reg & 3) + 8 * (reg >> 2);
      rw0[reg] = LOG2E * bf2f(rwp0[o]);
      rw1[reg] = LOG2E * bf2f(rwp1[o]);
    }
  }
  const short* rhp = rhTg + ((size_t)(h * 64 + qt)) * 4096;

  // staging offsets (inverse-swizzled).  waves 0/1: K rows; waves 2/3: V.
  int soff[8];
  const char* sbase;
  if (wave < 2) {
    sbase = (const char*)kg + (size_t)h * N * 128 + wave * 64 * 128;
#pragma unroll
    for (int it = 0; it < 8; ++it) {
      int c = it * 64 + lane, row = c >> 3;
      soff[it] = row * 128 + (((c & 7) << 4) ^ ((row & 7) << 4));
    }
  } else {
    sbase = (const char*)vTg + (size_t)h * 64 * 8192 + (wave - 2) * 128;
#pragma unroll
    for (int it = 0; it < 8; ++it) {
      int c = it * 64 + lane, r = c >> 3;
      soff[it] = r * 8192 + (((c & 7) << 4) ^ ((r & 7) << 4));
    }
  }
  const int sstep = (wave < 2) ? 16384 : 256;
  char* lreg = lds + wave * 8192;

  auto STAGE = [&](int i, int buf) {
    const char* sp = sbase + (size_t)i * sstep;
    char* lp = lreg + buf * 32768;
#pragma unroll
    for (int it = 0; it < 8; ++it) gload16(sp + soff[it], lp + it * 1024);
  };

  // fragment read offsets (within a buffer)
  const int swzq = (ql & 7) << 4;
  const int krow = (kt2 * 64 + kh2 * 32 + ql) * 128;
  const int kco0 = krow + ((0 * 32 + hi * 16) ^ swzq);
  const int kco1 = krow + ((1 * 32 + hi * 16) ^ swzq);
  const int kco2 = krow + ((2 * 32 + hi * 16) ^ swzq);
  const int kco3 = krow + ((3 * 32 + hi * 16) ^ swzq);
  const int vrow0 = 16384 + kt2 * 8192 + ql * 128;
  const int vrow1 = vrow0 + 32 * 128;
  const int vch0 = (kh2 * 64 + 0 * 32 + hi * 16) ^ swzq;
  const int vch1 = (kh2 * 64 + 1 * 32 + hi * 16) ^ swzq;
  const int vco0 = vrow0 + vch0;
  const int vco1 = vrow1 + vch0;
  const int vco2 = vrow0 + vch1;
  const int vco3 = vrow1 + vch1;

  f32x16 acc00 = {}, acc01 = {}, acc10 = {}, acc11 = {};
  float la0 = 0.f, lb0 = 0.f, la1 = 0.f, lb1 = 0.f;

  // prologue: stage tile 0 + rh(0); leaves exactly 10 vmem in flight
  STAGE(0, 0);
  unsigned short rA0 = (unsigned short)rhp[(size_t)kt2 * 64 + ql];
  unsigned short rA1 = (unsigned short)rhp[(size_t)kt2 * 64 + 32 + ql];
  unsigned short rB0 = 0, rB1 = 0;

  // 2x-unrolled pipelined loop: 16 pairs of (even i=2*ii, odd i=2*ii+1).
  for (int ii = 0; ii < 16; ++ii) {
    const int i = 2 * ii;
    // ---- even iter: compute buf0, prefetch tile i+1 into buf1 ----
    STAGE(i + 1, 1);
    rB0 = (unsigned short)rhp[(size_t)((i + 1) * 2 + kt2) * 64 + ql];
    rB1 = (unsigned short)rhp[(size_t)((i + 1) * 2 + kt2) * 64 + 32 + ql];
    asm volatile("s_waitcnt vmcnt(10)" ::: "memory");  // tile i + rh(i) landed
    barrier_pre();
    FLASH_BODY(0, rA0, rA1);
    barrier_post();
    // ---- odd iter: compute buf1, prefetch tile i+2 into buf0 ----
    if (i + 2 < 32) {
      STAGE(i + 2, 0);
      rA0 = (unsigned short)rhp[(size_t)((i + 2) * 2 + kt2) * 64 + ql];
      rA1 = (unsigned short)rhp[(size_t)((i + 2) * 2 + kt2) * 64 + 32 + ql];
      asm volatile("s_waitcnt vmcnt(10)" ::: "memory");
    } else {
      asm volatile("s_waitcnt vmcnt(0)" ::: "memory");
    }
    barrier_pre();
    FLASH_BODY(32768, rB0, rB1);
    barrier_post();
  }

  // ---- epilogue: cross-wave reduction of l and O (all vmem drained) ----
  float l0 = la0 + lb0, l1 = la1 + lb1;
  l0 += __shfl_xor(l0, 32);
  l1 += __shfl_xor(l1, 32);
  float* LS = (float*)lds;               // [4 waves][64 q]
  if (lane < 32) {
    LS[wave * 64 + ql] = l0;
    LS[wave * 64 + 32 + ql] = l1;
  }
  __syncthreads();
  const int eq = wave * 16 + (lane >> 2);     // this thread's q row (epilogue)
  const int cb = (lane & 3) * 16;             // this thread's 16-col chunk
  float inv = 1.0f / (LS[eq] + LS[64 + eq] + LS[128 + eq] + LS[192 + eq]);
  __syncthreads();
  float* OF = (float*)lds;               // [4 waves][64 q][64 c], c XOR-swizzled
#pragma unroll
  for (int qg2 = 0; qg2 < 2; ++qg2)
#pragma unroll
    for (int ct = 0; ct < 2; ++ct) {
      const f32x16& a = qg2 ? (ct ? acc11 : acc10) : (ct ? acc01 : acc00);
#pragma unroll
      for (int reg = 0; reg < 16; ++reg) {
        int q = qg2 * 32 + (reg & 3) + 8 * (reg >> 2) + 4 * hi;
        int c = ct * 32 + ql;
        OF[wave * 4096 + q * 64 + (c ^ ((q & 7) << 2))] = a[reg];
      }
    }
  __syncthreads();
  f32x4 osum[4] = {};
#pragma unroll
  for (int w = 0; w < 4; ++w)
#pragma unroll
    for (int j = 0; j < 4; ++j)
      osum[j] += *reinterpret_cast<const f32x4*>(
          &OF[w * 4096 + eq * 64 + ((cb + j * 4) ^ ((eq & 7) << 2))]);

  s16x8 hi8[2], lo8[2];
#pragma unroll
  for (int j = 0; j < 4; ++j)
#pragma unroll
    for (int e = 0; e < 4; ++e) {
      float o = osum[j][e] * inv;
      short oh = f2bf(o);
      float lo = o - bf2f(oh);
      int idx = j * 4 + e;
      hi8[idx >> 3][idx & 7] = oh;
      lo8[idx >> 3][idx & 7] = f2bf(lo);
    }
  size_t obase = (size_t)(i0 + eq) * 2304 + h * 64 + cb;
  *reinterpret_cast<s16x8*>(&aprime[obase]) = hi8[0];
  *reinterpret_cast<s16x8*>(&aprime[obase + 8]) = hi8[1];
  *reinterpret_cast<s16x8*>(&aprime[obase + 768]) = hi8[0];
  *reinterpret_cast<s16x8*>(&aprime[obase + 776]) = hi8[1];
  *reinterpret_cast<s16x8*>(&aprime[obase + 1536]) = lo8[0];
  *reinterpret_cast<s16x8*>(&aprime[obase + 1544]) = lo8[1];
}

// ---------------------------------------------------------------------------
extern "C" void kernel_launch(void* const* d_in, const int* in_sizes, int n_in,
                              void* d_out, int out_size, void* d_ws, size_t ws_size,
                              hipStream_t stream) {
  const float* x      = (const float*)d_in[0];
  const float* w_qkv  = (const float*)d_in[1];
  const float* b_qkv  = (const float*)d_in[2];
  const float* lora_A = (const float*)d_in[3];
  const float* lora_B = (const float*)d_in[4];
  const float* w_proj = (const float*)d_in[5];
  const float* b_proj = (const float*)d_in[6];
  const float* rel_h  = (const float*)d_in[7];
  const float* rel_w  = (const float*)d_in[8];
  float* out = (float*)d_out;

  char* ws = (char*)d_ws;
  short* weff   = (short*)(ws + 0);           // dead before flash
  short* xb     = (short*)(ws + 3538944);     // dead before flash
  short* vg     = (short*)(ws + 9830400);     // dead before flash
  short* aprime = (short*)(ws + 0);           // overlays the above
  short* qg     = (short*)(ws + 18874368);
  short* kg     = (short*)(ws + 25165824);
  short* vTg    = (short*)(ws + 31457280);
  short* rhT    = (short*)(ws + 37748736);
  short* rwg    = (short*)(ws + 44040192);
  short* wsp    = (short*)(ws + 50331648);    // -> total 53,870,592
  (void)ws_size; (void)in_sizes; (void)n_in; (void)out_size;

  k_weff<<<dim3((QKV * DIM + 255) / 256), dim3(256), 0, stream>>>(w_qkv, lora_A, lora_B, weff);
  k_x2bf<<<dim3(3072), dim3(256), 0, stream>>>(x, xb);
  k_wsplit<<<dim3(9, 768), dim3(256), 0, stream>>>(w_proj, wsp);
  k_gemm<12, 0, 128><<<dim3(32, 18), dim3(256), 0, stream>>>(xb, weff, b_qkv, qg, kg, vg, nullptr);
  k_vT<<<dim3(64, NH), dim3(256), 0, stream>>>(vg, vTg);
  k_relh<<<dim3(NH * 64), dim3(256), 0, stream>>>(qg, rel_h, rhT);
  k_relw<<<dim3(NH * 64), dim3(256), 0, stream>>>(qg, rel_w, rwg);
  k_flash<<<dim3(NH * 64), dim3(256), 0, stream>>>(qg, kg, vTg, rhT, rwg, aprime);
  k_gemm<36, 1, 64><<<dim3(64, 6), dim3(256), 0, stream>>>(aprime, wsp, b_proj, nullptr, nullptr, nullptr, out);
}

// Round 6
// 159.912 us; speedup vs baseline: 2.5929x; 1.0707x over previous
//
#include <hip/hip_runtime.h>
#include <stdint.h>

// ---------------------------------------------------------------------------
// Fused SAM-style attention block on MI355X (gfx950).  Round 6.
// Flash v6: BARRIER-FREE main loop.  Each wave owns a disjoint 32-key slice
// of the 128-key double tile and stages ITS OWN K/V slice (V packed 2 c-rows
// per 128B LDS row so the proven XOR-16 swizzle applies).  No cross-wave data
// -> no s_barrier in the loop; waves self-pace on own vmcnt(10).
// GEMMs keep r5's counted-vmcnt double-buffer (that part worked).
// ---------------------------------------------------------------------------

typedef __attribute__((ext_vector_type(4))) float f32x4;
typedef __attribute__((ext_vector_type(16))) float f32x16;
typedef __attribute__((ext_vector_type(4))) float fvec4;
typedef __attribute__((ext_vector_type(8))) short s16x8;
typedef __attribute__((ext_vector_type(4))) short s16x4;
typedef __attribute__((ext_vector_type(4))) unsigned u32x4;

constexpr int NH  = 12;
constexpr int HD  = 64;
constexpr int DIM = 768;
constexpr int N   = 4096;
constexpr int QKV = 2304;
constexpr float LOG2E  = 1.4426950408889634f;
constexpr float SCALE2 = 0.125f * LOG2E;   // SCALE * log2(e)

static __device__ __forceinline__ short f2bf(float f) {
  unsigned u = __builtin_bit_cast(unsigned, f);
  unsigned r = (u + 0x7FFFu + ((u >> 16) & 1u)) >> 16;  // RNE
  return (short)r;
}
static __device__ __forceinline__ float bf2f(short s) {
  unsigned u = ((unsigned)(unsigned short)s) << 16;
  return __builtin_bit_cast(float, u);
}
static __device__ __forceinline__ unsigned cvt_pk_bf16(float a, float b) {
  unsigned r;
  asm("v_cvt_pk_bf16_f32 %0, %1, %2" : "=v"(r) : "v"(a), "v"(b));
  return r;
}
static __device__ __forceinline__ float ex2(float x) {
  float r;
  asm("v_exp_f32 %0, %1" : "=v"(r) : "v"(x));
  return r;
}
static __device__ __forceinline__ void gload16(const void* g, void* l) {
  __builtin_amdgcn_global_load_lds(
      (const __attribute__((address_space(1))) void*)g,
      (__attribute__((address_space(3))) void*)l, 16, 0, 0);
}
static __device__ __forceinline__ void barrier_pre() {
  __builtin_amdgcn_s_barrier();
  __builtin_amdgcn_sched_barrier(0);
}
static __device__ __forceinline__ void barrier_post() {
  __builtin_amdgcn_sched_barrier(0);
  __builtin_amdgcn_s_barrier();
  __builtin_amdgcn_sched_barrier(0);
}

// ---------------------------------------------------------------------------
// K0: W_eff = w_qkv + lora_B @ lora_A  (bf16 out, [2304][768])
// ---------------------------------------------------------------------------
__global__ __launch_bounds__(256) void k_weff(const float* __restrict__ w_qkv,
                                              const float* __restrict__ lora_A,
                                              const float* __restrict__ lora_B,
                                              short* __restrict__ weff) {
  int e = blockIdx.x * 256 + threadIdx.x;
  if (e >= QKV * DIM) return;
  int r = e / DIM, c = e % DIM;
  float acc = w_qkv[e];
#pragma unroll
  for (int t = 0; t < 12; ++t) acc += lora_B[r * 12 + t] * lora_A[t * DIM + c];
  weff[e] = f2bf(acc);
}

// ---------------------------------------------------------------------------
// K0b: x fp32 -> bf16
// ---------------------------------------------------------------------------
__global__ __launch_bounds__(256) void k_x2bf(const float* __restrict__ x,
                                              short* __restrict__ xb) {
  int i = blockIdx.x * 256 + threadIdx.x;
  fvec4 v = *reinterpret_cast<const fvec4*>(x + (size_t)i * 4);
  s16x4 p;
  p[0] = f2bf(v[0]); p[1] = f2bf(v[1]); p[2] = f2bf(v[2]); p[3] = f2bf(v[3]);
  *reinterpret_cast<s16x4*>(xb + (size_t)i * 4) = p;
}

// ---------------------------------------------------------------------------
// K0c: w_proj -> split-bf16 B' [768][2304] = [Whi | Wlo | Whi]
// ---------------------------------------------------------------------------
__global__ __launch_bounds__(256) void k_wsplit(const float* __restrict__ w,
                                                short* __restrict__ ws) {
  int r = blockIdx.y;
  int kk = blockIdx.x * 256 + threadIdx.x;
  int blk = (kk >= 1536) ? 2 : (kk >= 768 ? 1 : 0);
  int c = kk - blk * 768;
  float wv = w[(size_t)r * 768 + c];
  short hi = f2bf(wv);
  ws[(size_t)r * 2304 + kk] = (blk == 1) ? f2bf(wv - bf2f(hi)) : hi;
}

// ---------------------------------------------------------------------------
// BMx128 MFMA GEMM, BK=64, double-buffered, counted vmcnt + raw barriers (r5).
// ---------------------------------------------------------------------------
template <int KIT, int MODE, int BM>
__global__ __launch_bounds__(256, 2) void k_gemm(const short* __restrict__ A,
                                                 const short* __restrict__ B,
                                                 const float* __restrict__ bias,
                                                 short* __restrict__ qo,
                                                 short* __restrict__ ko,
                                                 short* __restrict__ vo,
                                                 float* __restrict__ outf) {
  constexpr int MFR = BM / 32;              // A m-frags per wave
  constexpr int BUFB = BM * 128 + 16384;    // bytes per buffer (A + B tiles)
  __shared__ __align__(16) char lds[2 * BUFB];
  const int tid = threadIdx.x;
  const int wave = tid >> 6, lane = tid & 63, lr = lane & 15, lg = lane >> 4;
  const int wr = wave >> 1, wc = wave & 1;
  const int i0 = blockIdx.x * BM, j0 = blockIdx.y * 128;
  const int LDA = KIT * 128;  // row bytes

  size_t offA[MFR], offB[4];
#pragma unroll
  for (int it = 0; it < MFR; ++it) {
    int c = it * 256 + tid;
    int row = c >> 3;
    offA[it] = (size_t)row * LDA + (((c & 7) << 4) ^ ((row & 7) << 4));
  }
#pragma unroll
  for (int it = 0; it < 4; ++it) {
    int c = it * 256 + tid;
    int row = c >> 3;
    offB[it] = (size_t)row * LDA + (((c & 7) << 4) ^ ((row & 7) << 4));
  }
  const char* Ab = (const char*)A + (size_t)i0 * LDA;
  const char* Bb = (const char*)B + (size_t)j0 * LDA;

  auto STAGE = [&](int kt, int b) {
    char* base = lds + b * BUFB;
    const size_t kadd = (size_t)kt * 128;
#pragma unroll
    for (int it = 0; it < MFR; ++it)
      gload16(Ab + kadd + offA[it], base + wave * 1024 + it * 4096);
#pragma unroll
    for (int it = 0; it < 4; ++it)
      gload16(Bb + kadd + offB[it], base + BM * 128 + wave * 1024 + it * 4096);
  };

  const int swz = (lr & 7) << 4;
  const int ab = (wr * (BM / 2) + lr) * 128 + ((lg * 16) ^ swz);
  const int bb = BM * 128 + (wc * 64 + lr) * 128 + ((lg * 16) ^ swz);

  f32x4 acc[MFR][4] = {};

  STAGE(0, 0);
  for (int kt = 0; kt < KIT; ++kt) {
    const int buf = kt & 1;
    if (kt + 1 < KIT) {
      STAGE(kt + 1, buf ^ 1);
      if constexpr (BM == 128)
        asm volatile("s_waitcnt vmcnt(8)" ::: "memory");
      else
        asm volatile("s_waitcnt vmcnt(6)" ::: "memory");
    } else {
      asm volatile("s_waitcnt vmcnt(0)" ::: "memory");
    }
    barrier_pre();
    const char* bufp = lds + buf * BUFB;
#pragma unroll
    for (int ks2 = 0; ks2 < 2; ++ks2) {
      s16x8 af[MFR], bf_[4];
#pragma unroll
      for (int m = 0; m < MFR; ++m)
        af[m] = *reinterpret_cast<const s16x8*>(bufp + ((ab + m * 2048) ^ (ks2 << 6)));
#pragma unroll
      for (int n = 0; n < 4; ++n)
        bf_[n] = *reinterpret_cast<const s16x8*>(bufp + ((bb + n * 2048) ^ (ks2 << 6)));
#pragma unroll
      for (int m = 0; m < MFR; ++m)
#pragma unroll
        for (int n = 0; n < 4; ++n)
          acc[m][n] = __builtin_amdgcn_mfma_f32_16x16x32_bf16(af[m], bf_[n], acc[m][n], 0, 0, 0);
    }
    barrier_post();
  }

  if constexpr (MODE == 0) {
    const int three = j0 / 768;
    const int head = ((j0 % 768) >> 6) + wc;
    short* dst = (three == 0) ? qo : ((three == 1) ? ko : vo);
#pragma unroll
    for (int n = 0; n < 4; ++n) {
      const int col = n * 16 + lr;
      const float bj = bias[j0 + wc * 64 + col];
#pragma unroll
      for (int m = 0; m < MFR; ++m)
#pragma unroll
        for (int r = 0; r < 4; ++r) {
          int i = i0 + wr * (BM / 2) + m * 16 + lg * 4 + r;
          dst[((size_t)head * N + i) * HD + col] = f2bf(acc[m][n][r] + bj);
        }
    }
  } else {
#pragma unroll
    for (int n = 0; n < 4; ++n) {
      const int j = j0 + wc * 64 + n * 16 + lr;
      const float bj = bias[j];
#pragma unroll
      for (int m = 0; m < MFR; ++m)
#pragma unroll
        for (int r = 0; r < 4; ++r) {
          int i = i0 + wr * (BM / 2) + m * 16 + lg * 4 + r;
          outf[(size_t)i * 768 + j] = acc[m][n][r] + bj;
        }
    }
  }
}

// ---------------------------------------------------------------------------
// K1b: vT[h][c][i] = v[h][i][c]
// ---------------------------------------------------------------------------
__global__ __launch_bounds__(256) void k_vT(const short* __restrict__ vg,
                                            short* __restrict__ vTg) {
  __shared__ short ts[64 * 72];
  const int tid = threadIdx.x;
  const int i0 = blockIdx.x * 64;
  const int h = blockIdx.y;
#pragma unroll
  for (int it = 0; it < 2; ++it) {
    int ch = tid + 256 * it;
    int row = ch >> 3, cc = (ch & 7) * 8;
    *reinterpret_cast<s16x8*>(&ts[row * 72 + cc]) =
        *reinterpret_cast<const s16x8*>(&vg[((size_t)h * N + i0 + row) * HD + cc]);
  }
  __syncthreads();
#pragma unroll
  for (int it = 0; it < 2; ++it) {
    int ch = tid + 256 * it;
    int c = ch >> 3, ii = (ch & 7) * 8;
    s16x8 o;
#pragma unroll
    for (int j = 0; j < 8; ++j) o[j] = ts[(ii + j) * 72 + c];
    *reinterpret_cast<s16x8*>(&vTg[((size_t)h * HD + c) * N + i0 + ii]) = o;
  }
}

// ---------------------------------------------------------------------------
// K2a: rel_h via MFMA, stored TRANSPOSED: rhT[h][qh][kh][qw]
// ---------------------------------------------------------------------------
__global__ __launch_bounds__(256) void k_relh(const short* __restrict__ qg,
                                              const float* __restrict__ tab,
                                              short* __restrict__ rhT) {
  __shared__ short Ts[64 * 72];
  const int tid = threadIdx.x;
  const int wave = tid >> 6, lane = tid & 63, lr = lane & 15, lg = lane >> 4;
  const int h = blockIdx.x >> 6, qh = blockIdx.x & 63;
#pragma unroll
  for (int it = 0; it < 4; ++it) {
    int e = tid + 256 * it;
    int row = e >> 4, c4 = (e & 15) * 4;  // row = kh
    fvec4 v = *reinterpret_cast<const fvec4*>(tab + (size_t)(qh + 63 - row) * 64 + c4);
    s16x4 p;
    p[0] = f2bf(v[0]); p[1] = f2bf(v[1]); p[2] = f2bf(v[2]); p[3] = f2bf(v[3]);
    *reinterpret_cast<s16x4*>(&Ts[row * 72 + c4]) = p;
  }
  __syncthreads();
  const size_t qrow = (size_t)h * N + qh * 64 + wave * 16 + lr;
  const s16x8 a0 = *reinterpret_cast<const s16x8*>(qg + qrow * 64 + lg * 8);
  const s16x8 a1 = *reinterpret_cast<const s16x8*>(qg + qrow * 64 + 32 + lg * 8);
  f32x4 acc[4] = {};
#pragma unroll
  for (int ks2 = 0; ks2 < 2; ++ks2)
#pragma unroll
    for (int n = 0; n < 4; ++n) {
      s16x8 b = *reinterpret_cast<const s16x8*>(&Ts[(n * 16 + lr) * 72 + ks2 * 32 + lg * 8]);
      acc[n] = __builtin_amdgcn_mfma_f32_16x16x32_bf16(ks2 ? a1 : a0, b, acc[n], 0, 0, 0);
    }
  const size_t ob = ((size_t)(h * 64 + qh)) * 4096;
#pragma unroll
  for (int n = 0; n < 4; ++n) {
    s16x4 o;
#pragma unroll
    for (int r = 0; r < 4; ++r) o[r] = f2bf(acc[n][r]);
    *reinterpret_cast<s16x4*>(&rhT[ob + (size_t)(n * 16 + lr) * 64 + wave * 16 + lg * 4]) = o;
  }
}

// ---------------------------------------------------------------------------
// K2b: rel_w via U-GEMM + scatter.
// ---------------------------------------------------------------------------
__global__ __launch_bounds__(256) void k_relw(const short* __restrict__ qg,
                                              const float* __restrict__ tab,
                                              short* __restrict__ rwg) {
  __shared__ short Ts[128 * 72];
  const int tid = threadIdx.x;
  const int wave = tid >> 6, lane = tid & 63, lr = lane & 15, lg = lane >> 4;
  const int h = blockIdx.x >> 6, qh = blockIdx.x & 63;
#pragma unroll
  for (int it = 0; it < 8; ++it) {
    int e = tid + 256 * it;
    int row = e >> 4, c4 = (e & 15) * 4;  // row = d
    s16x4 p = {0, 0, 0, 0};
    if (row < 127) {
      fvec4 v = *reinterpret_cast<const fvec4*>(tab + (size_t)row * 64 + c4);
      p[0] = f2bf(v[0]); p[1] = f2bf(v[1]); p[2] = f2bf(v[2]); p[3] = f2bf(v[3]);
    }
    *reinterpret_cast<s16x4*>(&Ts[row * 72 + c4]) = p;
  }
  __syncthreads();
  const size_t qrow = (size_t)h * N + qh * 64 + wave * 16 + lr;
  const s16x8 a0 = *reinterpret_cast<const s16x8*>(qg + qrow * 64 + lg * 8);
  const s16x8 a1 = *reinterpret_cast<const s16x8*>(qg + qrow * 64 + 32 + lg * 8);
  f32x4 acc[8] = {};
#pragma unroll
  for (int ks2 = 0; ks2 < 2; ++ks2)
#pragma unroll
    for (int n = 0; n < 8; ++n) {
      s16x8 b = *reinterpret_cast<const s16x8*>(&Ts[(n * 16 + lr) * 72 + ks2 * 32 + lg * 8]);
      acc[n] = __builtin_amdgcn_mfma_f32_16x16x32_bf16(ks2 ? a1 : a0, b, acc[n], 0, 0, 0);
    }
  const size_t ob = ((size_t)h * N + qh * 64) * 64;
#pragma unroll
  for (int n = 0; n < 8; ++n) {
    int d = n * 16 + lr;
#pragma unroll
    for (int r = 0; r < 4; ++r) {
      int qw = wave * 16 + lg * 4 + r;
      int kw = qw + 63 - d;
      if ((unsigned)kw < 64u) rwg[ob + (size_t)qw * 64 + kw] = f2bf(acc[n][r]);
    }
  }
}

// ---------------------------------------------------------------------------
// K3: flash attention v6.  Barrier-free: each wave stages + consumes its OWN
// 32-key slice per 128-key double tile.  Wave LDS region (8KB/buffer):
//   K slice  @0    : 32 rows x 128B (row = own key, cols = 64 d)
//   V slice  @4096 : 32 rows x 128B (row r: bytes 0-63 = V^T[c=r][own 32 keys],
//                                    bytes 64-127 = V^T[c=r+32][own 32 keys])
// Both XOR-16 swizzled.  dbuf at +32768.  Q, rel_w in regs; rel_h global
// prefetch (parity regs).  Single __syncthreads before epilogue reduction.
// ---------------------------------------------------------------------------
#define QG_BLOCK(QB0, QB1, QB2, QB3, RW, RH2, ACC0, ACC1, LA, LB)              \
  do {                                                                         \
    f32x16 sa = {};                                                            \
    __builtin_amdgcn_s_setprio(1);                                             \
    sa = __builtin_amdgcn_mfma_f32_32x32x16_bf16(kf0, QB0, sa, 0, 0, 0);       \
    sa = __builtin_amdgcn_mfma_f32_32x32x16_bf16(kf1, QB1, sa, 0, 0, 0);       \
    sa = __builtin_amdgcn_mfma_f32_32x32x16_bf16(kf2, QB2, sa, 0, 0, 0);       \
    sa = __builtin_amdgcn_mfma_f32_32x32x16_bf16(kf3, QB3, sa, 0, 0, 0);       \
    __builtin_amdgcn_s_setprio(0);                                             \
    float p[16];                                                               \
    _Pragma("unroll")                                                          \
    for (int reg = 0; reg < 16; ++reg)                                         \
      p[reg] = ex2(fmaf(sa[reg], SCALE2, RH2 + RW[reg]));                      \
    float t0 = (p[0] + p[1]) + (p[2] + p[3]);                                  \
    float t1 = (p[4] + p[5]) + (p[6] + p[7]);                                  \
    float t2 = (p[8] + p[9]) + (p[10] + p[11]);                                \
    float t3 = (p[12] + p[13]) + (p[14] + p[15]);                              \
    LA += t0 + t1;                                                             \
    LB += t2 + t3;                                                             \
    unsigned w00 = cvt_pk_bf16(p[0], p[1]),   w01 = cvt_pk_bf16(p[2], p[3]);   \
    unsigned w10 = cvt_pk_bf16(p[4], p[5]),   w11 = cvt_pk_bf16(p[6], p[7]);   \
    unsigned w20 = cvt_pk_bf16(p[8], p[9]),   w21 = cvt_pk_bf16(p[10], p[11]); \
    unsigned w30 = cvt_pk_bf16(p[12], p[13]), w31 = cvt_pk_bf16(p[14], p[15]); \
    asm("v_permlane32_swap_b32 %0, %1" : "+v"(w00), "+v"(w10));                \
    asm("v_permlane32_swap_b32 %0, %1" : "+v"(w01), "+v"(w11));                \
    asm("v_permlane32_swap_b32 %0, %1" : "+v"(w20), "+v"(w30));                \
    asm("v_permlane32_swap_b32 %0, %1" : "+v"(w21), "+v"(w31));                \
    u32x4 u0 = {w00, w01, w10, w11};                                           \
    u32x4 u1 = {w20, w21, w30, w31};                                           \
    s16x8 pa0 = __builtin_bit_cast(s16x8, u0);                                 \
    s16x8 pa1 = __builtin_bit_cast(s16x8, u1);                                 \
    __builtin_amdgcn_s_setprio(1);                                             \
    ACC0 = __builtin_amdgcn_mfma_f32_32x32x16_bf16(pa0, vf0, ACC0, 0, 0, 0);   \
    ACC0 = __builtin_amdgcn_mfma_f32_32x32x16_bf16(pa1, vf2, ACC0, 0, 0, 0);   \
    ACC1 = __builtin_amdgcn_mfma_f32_32x32x16_bf16(pa0, vf1, ACC1, 0, 0, 0);   \
    ACC1 = __builtin_amdgcn_mfma_f32_32x32x16_bf16(pa1, vf3, ACC1, 0, 0, 0);   \
    __builtin_amdgcn_s_setprio(0);                                             \
  } while (0)

#define FLASH_BODY(BUFOFF, RHU0, RHU1)                                         \
  do {                                                                         \
    const char* bufp = wb + (BUFOFF);                                          \
    s16x8 kf0 = *reinterpret_cast<const s16x8*>(bufp + kco0);                  \
    s16x8 kf1 = *reinterpret_cast<const s16x8*>(bufp + kco1);                  \
    s16x8 kf2 = *reinterpret_cast<const s16x8*>(bufp + kco2);                  \
    s16x8 kf3 = *reinterpret_cast<const s16x8*>(bufp + kco3);                  \
    s16x8 vf0 = *reinterpret_cast<const s16x8*>(bufp + vco0);                  \
    s16x8 vf1 = *reinterpret_cast<const s16x8*>(bufp + vco1);                  \
    s16x8 vf2 = *reinterpret_cast<const s16x8*>(bufp + vco2);                  \
    s16x8 vf3 = *reinterpret_cast<const s16x8*>(bufp + vco3);                  \
    const float rh20 = LOG2E * bf2f((short)(RHU0));                            \
    const float rh21 = LOG2E * bf2f((short)(RHU1));                            \
    QG_BLOCK(qb00, qb01, qb02, qb03, rw0, rh20, acc00, acc01, la0, lb0);       \
    QG_BLOCK(qb10, qb11, qb12, qb13, rw1, rh21, acc10, acc11, la1, lb1);       \
  } while (0)

__global__ __launch_bounds__(256, 2) void k_flash(const short* __restrict__ qg,
                                                  const short* __restrict__ kg,
                                                  const short* __restrict__ vTg,
                                                  const short* __restrict__ rhTg,
                                                  const short* __restrict__ rwg,
                                                  short* __restrict__ aprime) {
  __shared__ __align__(16) char lds[65536];
  const int tid = threadIdx.x;
  const int wave = tid >> 6, lane = tid & 63;
  const int ql = lane & 31, hi = lane >> 5;
  const int kt2 = wave & 1, kh2 = wave >> 1;
  const int bid = blockIdx.x;
  const int id = (bid & 7) * 96 + (bid >> 3);  // bijective XCD swizzle (768%8==0)
  const int h = id >> 6, qt = id & 63;
  const int i0 = qt * 64;

  // Q fragments in registers
  const short* q0p = qg + ((size_t)h * N + i0 + ql) * 64 + hi * 8;
  const short* q1p = q0p + 32 * 64;
  const s16x8 qb00 = *reinterpret_cast<const s16x8*>(q0p);
  const s16x8 qb01 = *reinterpret_cast<const s16x8*>(q0p + 16);
  const s16x8 qb02 = *reinterpret_cast<const s16x8*>(q0p + 32);
  const s16x8 qb03 = *reinterpret_cast<const s16x8*>(q0p + 48);
  const s16x8 qb10 = *reinterpret_cast<const s16x8*>(q1p);
  const s16x8 qb11 = *reinterpret_cast<const s16x8*>(q1p + 16);
  const s16x8 qb12 = *reinterpret_cast<const s16x8*>(q1p + 32);
  const s16x8 qb13 = *reinterpret_cast<const s16x8*>(q1p + 48);

  // rel_w preload (tile-invariant)
  f32x16 rw0, rw1;
  {
    const short* rwp0 = rwg + ((size_t)h * N + i0 + ql) * 64 + kh2 * 32 + hi * 4;
    const short* rwp1 = rwp0 + 32 * 64;
#pragma unroll
    for (int reg = 0; reg < 16; ++reg) {
      int o = (reg & 3) + 8 * (reg >> 2);
      rw0[reg] = LOG2E * bf2f(rwp0[o]);
      rw1[reg] = LOG2E * bf2f(rwp1[o]);
    }
  }
  const short* rhp = rhTg + ((size_t)(h * 64 + qt)) * 4096;

  // own-slice staging offsets (inverse-swizzled)
  const int kbrow = kt2 * 64 + kh2 * 32;   // wave's first key (row / key units)
  int koff[4], voff[4];
#pragma unroll
  for (int it = 0; it < 4; ++it) {
    int c = it * 64 + lane;
    int row = c >> 3, pos = c & 7, s = pos ^ (row & 7);
    koff[it] = (kbrow + row) * 128 + s * 16;
  }
#pragma unroll
  for (int it = 0; it < 4; ++it) {
    int c = it * 64 + lane;
    int r = c >> 3, pos = c & 7, s = pos ^ (r & 7);
    voff[it] = (r + ((s >> 2) << 5)) * 8192 + (kbrow + ((s & 3) << 3)) * 2;
  }
  const char* kgb = (const char*)kg + (size_t)h * N * 128;
  const char* vgb = (const char*)vTg + (size_t)h * 64 * 8192;
  char* wb = lds + wave * 8192;

  auto STAGE = [&](int i, int buf) {
    const char* kp = kgb + (size_t)i * 16384;   // 128 rows x 128B per dbl tile
    const char* vp = vgb + (size_t)i * 256;     // 128 keys x 2B
    char* lp = wb + buf * 32768;
#pragma unroll
    for (int it = 0; it < 4; ++it) gload16(kp + koff[it], lp + it * 1024);
#pragma unroll
    for (int it = 0; it < 4; ++it) gload16(vp + voff[it], lp + 4096 + it * 1024);
  };

  // fragment read offsets (relative to wave region + buffer)
  const int swzq = (ql & 7) << 4;
  const int kco0 = ql * 128 + ((0 * 32 + hi * 16) ^ swzq);
  const int kco1 = ql * 128 + ((1 * 32 + hi * 16) ^ swzq);
  const int kco2 = ql * 128 + ((2 * 32 + hi * 16) ^ swzq);
  const int kco3 = ql * 128 + ((3 * 32 + hi * 16) ^ swzq);
  const int vco0 = 4096 + ql * 128 + ((0 * 64 + 0 * 32 + hi * 16) ^ swzq);  // ks0 ct0
  const int vco1 = 4096 + ql * 128 + ((1 * 64 + 0 * 32 + hi * 16) ^ swzq);  // ks0 ct1
  const int vco2 = 4096 + ql * 128 + ((0 * 64 + 1 * 32 + hi * 16) ^ swzq);  // ks1 ct0
  const int vco3 = 4096 + ql * 128 + ((1 * 64 + 1 * 32 + hi * 16) ^ swzq);  // ks1 ct1

  f32x16 acc00 = {}, acc01 = {}, acc10 = {}, acc11 = {};
  float la0 = 0.f, lb0 = 0.f, la1 = 0.f, lb1 = 0.f;

  // prologue: tile 0 + rh(0) -> 10 vmem in flight
  STAGE(0, 0);
  unsigned short rA0 = (unsigned short)rhp[(size_t)kt2 * 64 + ql];
  unsigned short rA1 = (unsigned short)rhp[(size_t)kt2 * 64 + 32 + ql];
  unsigned short rB0 = 0, rB1 = 0;

  for (int ii = 0; ii < 16; ++ii) {
    const int i = 2 * ii;
    // even iter: compute buf0, prefetch i+1 into buf1
    STAGE(i + 1, 1);
    rB0 = (unsigned short)rhp[(size_t)((i + 1) * 2 + kt2) * 64 + ql];
    rB1 = (unsigned short)rhp[(size_t)((i + 1) * 2 + kt2) * 64 + 32 + ql];
    asm volatile("s_waitcnt vmcnt(10)" ::: "memory");  // own tile i + rh(i)
    __builtin_amdgcn_sched_barrier(0);
    FLASH_BODY(0, rA0, rA1);
    // odd iter: compute buf1, prefetch i+2 into buf0
    if (i + 2 < 32) {
      STAGE(i + 2, 0);
      rA0 = (unsigned short)rhp[(size_t)((i + 2) * 2 + kt2) * 64 + ql];
      rA1 = (unsigned short)rhp[(size_t)((i + 2) * 2 + kt2) * 64 + 32 + ql];
      asm volatile("s_waitcnt vmcnt(10)" ::: "memory");
    } else {
      asm volatile("s_waitcnt vmcnt(0)" ::: "memory");
    }
    __builtin_amdgcn_sched_barrier(0);
    FLASH_BODY(32768, rB0, rB1);
  }

  // ---- epilogue: cross-wave reduction of l and O ----
  __syncthreads();   // waves are skewed; sync before reusing LDS as scratch
  float l0 = la0 + lb0, l1 = la1 + lb1;
  l0 += __shfl_xor(l0, 32);
  l1 += __shfl_xor(l1, 32);
  float* LS = (float*)lds;               // [4 waves][64 q]
  if (lane < 32) {
    LS[wave * 64 + ql] = l0;
    LS[wave * 64 + 32 + ql] = l1;
  }
  __syncthreads();
  const int eq = wave * 16 + (lane >> 2);     // this thread's q row (epilogue)
  const int cb = (lane & 3) * 16;             // this thread's 16-col chunk
  float inv = 1.0f / (LS[eq] + LS[64 + eq] + LS[128 + eq] + LS[192 + eq]);
  __syncthreads();
  float* OF = (float*)lds;               // [4 waves][64 q][64 c], c XOR-swizzled
#pragma unroll
  for (int qg2 = 0; qg2 < 2; ++qg2)
#pragma unroll
    for (int ct = 0; ct < 2; ++ct) {
      const f32x16& a = qg2 ? (ct ? acc11 : acc10) : (ct ? acc01 : acc00);
#pragma unroll
      for (int reg = 0; reg < 16; ++reg) {
        int q = qg2 * 32 + (reg & 3) + 8 * (reg >> 2) + 4 * hi;
        int c = ct * 32 + ql;
        OF[wave * 4096 + q * 64 + (c ^ ((q & 7) << 2))] = a[reg];
      }
    }
  __syncthreads();
  f32x4 osum[4] = {};
#pragma unroll
  for (int w = 0; w < 4; ++w)
#pragma unroll
    for (int j = 0; j < 4; ++j)
      osum[j] += *reinterpret_cast<const f32x4*>(
          &OF[w * 4096 + eq * 64 + ((cb + j * 4) ^ ((eq & 7) << 2))]);

  s16x8 hi8[2], lo8[2];
#pragma unroll
  for (int j = 0; j < 4; ++j)
#pragma unroll
    for (int e = 0; e < 4; ++e) {
      float o = osum[j][e] * inv;
      short oh = f2bf(o);
      float lo = o - bf2f(oh);
      int idx = j * 4 + e;
      hi8[idx >> 3][idx & 7] = oh;
      lo8[idx >> 3][idx & 7] = f2bf(lo);
    }
  size_t obase = (size_t)(i0 + eq) * 2304 + h * 64 + cb;
  *reinterpret_cast<s16x8*>(&aprime[obase]) = hi8[0];
  *reinterpret_cast<s16x8*>(&aprime[obase + 8]) = hi8[1];
  *reinterpret_cast<s16x8*>(&aprime[obase + 768]) = hi8[0];
  *reinterpret_cast<s16x8*>(&aprime[obase + 776]) = hi8[1];
  *reinterpret_cast<s16x8*>(&aprime[obase + 1536]) = lo8[0];
  *reinterpret_cast<s16x8*>(&aprime[obase + 1544]) = lo8[1];
}

// ---------------------------------------------------------------------------
extern "C" void kernel_launch(void* const* d_in, const int* in_sizes, int n_in,
                              void* d_out, int out_size, void* d_ws, size_t ws_size,
                              hipStream_t stream) {
  const float* x      = (const float*)d_in[0];
  const float* w_qkv  = (const float*)d_in[1];
  const float* b_qkv  = (const float*)d_in[2];
  const float* lora_A = (const float*)d_in[3];
  const float* lora_B = (const float*)d_in[4];
  const float* w_proj = (const float*)d_in[5];
  const float* b_proj = (const float*)d_in[6];
  const float* rel_h  = (const float*)d_in[7];
  const float* rel_w  = (const float*)d_in[8];
  float* out = (float*)d_out;

  char* ws = (char*)d_ws;
  short* weff   = (short*)(ws + 0);           // dead before flash
  short* xb     = (short*)(ws + 3538944);     // dead before flash
  short* vg     = (short*)(ws + 9830400);     // dead before flash
  short* aprime = (short*)(ws + 0);           // overlays the above
  short* qg     = (short*)(ws + 18874368);
  short* kg     = (short*)(ws + 25165824);
  short* vTg    = (short*)(ws + 31457280);
  short* rhT    = (short*)(ws + 37748736);
  short* rwg    = (short*)(ws + 44040192);
  short* wsp    = (short*)(ws + 50331648);    // -> total 53,870,592
  (void)ws_size; (void)in_sizes; (void)n_in; (void)out_size;

  k_weff<<<dim3((QKV * DIM + 255) / 256), dim3(256), 0, stream>>>(w_qkv, lora_A, lora_B, weff);
  k_x2bf<<<dim3(3072), dim3(256), 0, stream>>>(x, xb);
  k_wsplit<<<dim3(9, 768), dim3(256), 0, stream>>>(w_proj, wsp);
  k_gemm<12, 0, 128><<<dim3(32, 18), dim3(256), 0, stream>>>(xb, weff, b_qkv, qg, kg, vg, nullptr);
  k_vT<<<dim3(64, NH), dim3(256), 0, stream>>>(vg, vTg);
  k_relh<<<dim3(NH * 64), dim3(256), 0, stream>>>(qg, rel_h, rhT);
  k_relw<<<dim3(NH * 64), dim3(256), 0, stream>>>(qg, rel_w, rwg);
  k_flash<<<dim3(NH * 64), dim3(256), 0, stream>>>(qg, kg, vTg, rhT, rwg, aprime);
  k_gemm<36, 1, 64><<<dim3(64, 6), dim3(256), 0, stream>>>(aprime, wsp, b_proj, nullptr, nullptr, nullptr, out);
}